// Round 4
// baseline (557.027 us; speedup 1.0000x reference)
//
#include <hip/hip_runtime.h>

#define NG 128
#define G3 (NG*NG*NG)
#define NT 16               // tiles per axis (8 cells per tile)
#define NTILES (NT*NT*NT)   // 4096
#define HCELLS 1000         // 10x10x10 halo cells per tile

__device__ __constant__ const float c_DX      = 1.0f/128.0f;
__device__ __constant__ const float c_INV_DX  = 128.0f;

#define DT      1e-4f
#define P_VOL   ((1.0f/256.0f)*(1.0f/256.0f))
#define P_MASS  P_VOL
#define MU0     (5000.0f/(2.0f*1.2f))
#define LAM0    (5000.0f*0.2f/(1.2f*0.6f))

// 64-byte packed particle record, written in sorted (tile-bucketed) order
// r0 = {px, py, pz, particle_id}
// r1 = {aff0..3}, r2 = {aff4..7}, r3 = {aff8, mv0, mv1, mv2}
struct __align__(16) PRec {
    float4 r0, r1, r2, r3;
};

// ---------------- 3x3 SVD via Jacobi on A^T A ----------------
__device__ inline void jacobi_rot(float S[3][3], float V[3][3], int p, int q) {
    float apq = S[p][q];
    if (fabsf(apq) < 1e-24f) return;
    float tau = (S[q][q] - S[p][p]) / (2.0f * apq);
    float t = copysignf(1.0f, tau) / (fabsf(tau) + sqrtf(1.0f + tau*tau));
    float c = rsqrtf(1.0f + t*t);
    float sn = t * c;
    #pragma unroll
    for (int k = 0; k < 3; ++k) {
        float Spk = S[p][k], Sqk = S[q][k];
        S[p][k] = c*Spk - sn*Sqk;
        S[q][k] = sn*Spk + c*Sqk;
    }
    #pragma unroll
    for (int k = 0; k < 3; ++k) {
        float Skp = S[k][p], Skq = S[k][q];
        S[k][p] = c*Skp - sn*Skq;
        S[k][q] = sn*Skp + c*Skq;
    }
    #pragma unroll
    for (int k = 0; k < 3; ++k) {
        float Vkp = V[k][p], Vkq = V[k][q];
        V[k][p] = c*Vkp - sn*Vkq;
        V[k][q] = sn*Vkp + c*Vkq;
    }
}

__device__ inline void svd3(const float A[9], float U[9], float sv[3], float V[9]) {
    float S[3][3];
    #pragma unroll
    for (int i = 0; i < 3; ++i)
        #pragma unroll
        for (int j = 0; j < 3; ++j) {
            float acc = 0.f;
            #pragma unroll
            for (int k = 0; k < 3; ++k) acc += A[k*3+i]*A[k*3+j];
            S[i][j] = acc;
        }
    float Vm[3][3] = {{1.f,0.f,0.f},{0.f,1.f,0.f},{0.f,0.f,1.f}};
    #pragma unroll
    for (int sweep = 0; sweep < 4; ++sweep) {
        jacobi_rot(S, Vm, 0, 1);
        jacobi_rot(S, Vm, 0, 2);
        jacobi_rot(S, Vm, 1, 2);
    }
    float lam[3] = {S[0][0], S[1][1], S[2][2]};
    int i0 = 0, i1 = 1, i2 = 2, t;
    if (lam[i0] < lam[i1]) { t = i0; i0 = i1; i1 = t; }
    if (lam[i0] < lam[i2]) { t = i0; i0 = i2; i2 = t; }
    if (lam[i1] < lam[i2]) { t = i1; i1 = i2; i2 = t; }
    int ord[3] = {i0, i1, i2};
    #pragma unroll
    for (int c = 0; c < 3; ++c) {
        int s_ = ord[c];
        float l = fmaxf(lam[s_], 0.f);
        float sval = sqrtf(l);
        sv[c] = sval;
        float v0 = Vm[0][s_], v1 = Vm[1][s_], v2 = Vm[2][s_];
        V[0*3+c] = v0; V[1*3+c] = v1; V[2*3+c] = v2;
        float inv = (sval > 1e-12f) ? 1.0f/sval : 0.f;
        U[0*3+c] = (A[0]*v0 + A[1]*v1 + A[2]*v2)*inv;
        U[1*3+c] = (A[3]*v0 + A[4]*v1 + A[5]*v2)*inv;
        U[2*3+c] = (A[6]*v0 + A[7]*v1 + A[8]*v2)*inv;
    }
}

// ---------------- binning helpers ----------------
__device__ inline void particle_base(float px, float py, float pz,
                                     int& bi, int& bj, int& bk,
                                     float& fx0, float& fx1, float& fx2) {
    float bxf = floorf(px*c_INV_DX - 0.5f);
    float byf = floorf(py*c_INV_DX - 0.5f);
    float bzf = floorf(pz*c_INV_DX - 0.5f);
    bi = (int)bxf; bj = (int)byf; bk = (int)bzf;
    bi = min(max(bi, 0), NG-3); bj = min(max(bj, 0), NG-3); bk = min(max(bk, 0), NG-3);
    fx0 = px*c_INV_DX - bxf;
    fx1 = py*c_INV_DX - byf;
    fx2 = pz*c_INV_DX - bzf;
}

__global__ void __launch_bounds__(256)
count_kernel(const float* __restrict__ x, int* __restrict__ tile_count, int N) {
    int n = blockIdx.x*256 + threadIdx.x;
    if (n >= N) return;
    int bi, bj, bk; float f0, f1, f2;
    particle_base(x[3*n+0], x[3*n+1], x[3*n+2], bi, bj, bk, f0, f1, f2);
    int tile = ((bi >> 3)*NT + (bj >> 3))*NT + (bk >> 3);
    atomicAdd(&tile_count[tile], 1);
}

// exclusive scan of 4096 tile counts, single block of 256 threads x 16 elems
__global__ void __launch_bounds__(256)
scan_kernel(const int* __restrict__ count, int* __restrict__ offset) {
    __shared__ int part[256];
    int t = threadIdx.x;
    int base = t*16;
    int local[16];
    int s = 0;
    #pragma unroll
    for (int i = 0; i < 16; ++i) { local[i] = s; s += count[base+i]; }
    part[t] = s;
    __syncthreads();
    for (int off = 1; off < 256; off <<= 1) {
        int v = (t >= off) ? part[t-off] : 0;
        __syncthreads();
        part[t] += v;
        __syncthreads();
    }
    int prev = (t == 0) ? 0 : part[t-1];
    #pragma unroll
    for (int i = 0; i < 16; ++i) offset[base+i] = prev + local[i];
    if (t == 255) offset[NTILES] = prev + s;
}

// ---------------- pre-pass: all per-particle math, coalesced reads ----------------
__global__ void __launch_bounds__(256)
pre_kernel(const float* __restrict__ x, const float* __restrict__ v,
           const float* __restrict__ Cin, const float* __restrict__ Fin,
           const float* __restrict__ Jp_in, const int* __restrict__ material,
           const int* __restrict__ offset, int* __restrict__ cursor,
           PRec* __restrict__ rec, float* __restrict__ out, int N) {
    int n = blockIdx.x*256 + threadIdx.x;
    if (n >= N) return;

    float px = x[3*n+0], py = x[3*n+1], pz = x[3*n+2];
    int bi, bj, bk; float f0, f1, f2;
    particle_base(px, py, pz, bi, bj, bk, f0, f1, f2);

    float Cm[9], Fm[9];
    #pragma unroll
    for (int i = 0; i < 9; ++i) { Cm[i] = Cin[9*n+i]; Fm[i] = Fin[9*n+i]; }

    // Fn = (I + DT*C) @ F
    float Fn[9];
    #pragma unroll
    for (int i = 0; i < 3; ++i)
        #pragma unroll
        for (int k = 0; k < 3; ++k) {
            float acc = Fm[i*3+k];
            #pragma unroll
            for (int j = 0; j < 3; ++j) acc += DT * Cm[i*3+j] * Fm[j*3+k];
            Fn[i*3+k] = acc;
        }

    float Jp = Jp_in[n];
    int mat = material[n];
    float h = expf(10.0f*(1.0f - Jp));
    h = fminf(fmaxf(h, 0.1f), 5.0f);
    if (mat == 1) h = 0.3f;
    float mu = (mat == 0) ? 0.0f : MU0*h;
    float la = LAM0*h;

    float U[9], V[9], sv[3];
    svd3(Fn, U, sv, V);

    float J = 1.0f;
    float sig[3];
    #pragma unroll
    for (int d = 0; d < 2; ++d) {
        float s = sv[d];
        float ns = (mat == 2) ? fminf(fmaxf(s, 1.0f-0.025f), 1.0f+0.0045f) : s;
        Jp = Jp * s / ns;
        sig[d] = ns;
        J *= ns;
    }
    sig[2] = sv[2];

    if (mat == 0) {
        float sj = sqrtf(J);
        Fn[0]=sj; Fn[1]=0; Fn[2]=0; Fn[3]=0; Fn[4]=sj; Fn[5]=0; Fn[6]=0; Fn[7]=0; Fn[8]=sj;
    } else if (mat == 2) {
        #pragma unroll
        for (int i = 0; i < 3; ++i)
            #pragma unroll
            for (int k = 0; k < 3; ++k) {
                float acc = 0.f;
                #pragma unroll
                for (int j = 0; j < 3; ++j) acc += U[i*3+j]*sig[j]*V[k*3+j];
                Fn[i*3+k] = acc;
            }
    }

    float R[9];
    #pragma unroll
    for (int i = 0; i < 3; ++i)
        #pragma unroll
        for (int k = 0; k < 3; ++k) {
            float acc = 0.f;
            #pragma unroll
            for (int j = 0; j < 3; ++j) acc += U[i*3+j]*V[k*3+j];
            R[i*3+k] = acc;
        }

    float press = la * J * (J - 1.0f);
    float scale = -DT * P_VOL * 4.0f * c_INV_DX * c_INV_DX;
    float aff[9];
    #pragma unroll
    for (int i = 0; i < 3; ++i)
        #pragma unroll
        for (int k = 0; k < 3; ++k) {
            float acc = 0.f;
            #pragma unroll
            for (int j = 0; j < 3; ++j) acc += (Fn[i*3+j]-R[i*3+j])*Fn[k*3+j];
            acc = 2.0f*mu*acc;
            if (i == k) acc += press;
            aff[i*3+k] = scale*acc + P_MASS*Cm[i*3+k];
        }

    float* po = out + (size_t)n*25;
    po[6] = Jp;
    #pragma unroll
    for (int i = 0; i < 9; ++i) po[7+i] = Fn[i];

    // sorted slot
    int tile = ((bi >> 3)*NT + (bj >> 3))*NT + (bk >> 3);
    int pos = offset[tile] + atomicAdd(&cursor[tile], 1);

    // one full 64-B line, written with 4x float4
    float4* rp = (float4*)&rec[pos];
    float4 r0; r0.x = px; r0.y = py; r0.z = pz; r0.w = __int_as_float(n);
    rp[0] = r0;
    rp[1] = make_float4(aff[0], aff[1], aff[2], aff[3]);
    rp[2] = make_float4(aff[4], aff[5], aff[6], aff[7]);
    rp[3] = make_float4(aff[8], P_MASS*v[3*n+0], P_MASS*v[3*n+1], P_MASS*v[3*n+2]);
}

// ---------------- P2G: LDS accumulate -> private halo buffer (no atomics) ------
__global__ void __launch_bounds__(256)
p2g_tile_kernel(const PRec* __restrict__ rec, const int* __restrict__ offset,
                float4* __restrict__ halo) {
    int tile = blockIdx.x;
    int beg = offset[tile], end = offset[tile+1];

    __shared__ float lds[4][HCELLS];   // SoA: [comp][10*10*10 halo cells]
    for (int c = threadIdx.x; c < HCELLS; c += 256) {
        lds[0][c] = 0.f; lds[1][c] = 0.f; lds[2][c] = 0.f; lds[3][c] = 0.f;
    }
    __syncthreads();

    int tx8 = (tile / (NT*NT)) << 3;
    int ty8 = ((tile / NT) % NT) << 3;
    int tz8 = (tile % NT) << 3;

    for (int p = beg + (int)threadIdx.x; p < end; p += 256) {
        const float4* rp = (const float4*)&rec[p];
        float4 r0 = rp[0];
        float4 r1 = rp[1];
        float4 r2 = rp[2];
        float4 r3 = rp[3];

        int bi, bj, bk; float fx0, fx1, fx2;
        particle_base(r0.x, r0.y, r0.z, bi, bj, bk, fx0, fx1, fx2);

        float wx[3], wy[3];
        wx[0] = 0.5f*(1.5f-fx0)*(1.5f-fx0); wx[1] = 0.75f-(fx0-1.f)*(fx0-1.f); wx[2] = 0.5f*(fx0-0.5f)*(fx0-0.5f);
        wy[0] = 0.5f*(1.5f-fx1)*(1.5f-fx1); wy[1] = 0.75f-(fx1-1.f)*(fx1-1.f); wy[2] = 0.5f*(fx1-0.5f)*(fx1-0.5f);

        float a0 = r1.x, a1 = r1.y, a2 = r1.z, a3 = r1.w;
        float a4 = r2.x, a5 = r2.y, a6 = r2.z, a7 = r2.w;
        float a8 = r3.x, mv0 = r3.y, mv1 = r3.z, mv2 = r3.w;

        int offi = bi - tx8, offj = bj - ty8, offk = bk - tz8;
        #pragma unroll
        for (int i = 0; i < 3; ++i) {
            float dpx = ((float)i - fx0)*c_DX;
            #pragma unroll
            for (int j = 0; j < 3; ++j) {
                float wgt = wx[i]*wy[j];     // reference uses only x,y weight factors
                float dpy = ((float)j - fx1)*c_DX;
                int c0 = ((offi+i)*10 + (offj+j))*10 + offk;
                float wm = wgt*P_MASS;
                #pragma unroll
                for (int k = 0; k < 3; ++k) {
                    float dpz = ((float)k - fx2)*c_DX;
                    float mx = wgt*(mv0 + a0*dpx + a1*dpy + a2*dpz);
                    float my = wgt*(mv1 + a3*dpx + a4*dpy + a5*dpz);
                    float mz = wgt*(mv2 + a6*dpx + a7*dpy + a8*dpz);
                    int c = c0 + k;
                    atomicAdd(&lds[0][c], mx);
                    atomicAdd(&lds[1][c], my);
                    atomicAdd(&lds[2][c], mz);
                    atomicAdd(&lds[3][c], wm);
                }
            }
        }
    }
    __syncthreads();

    // dense flush: plain coalesced float4 stores, every tile writes all cells
    float4* hb = halo + (size_t)tile * HCELLS;
    for (int c = threadIdx.x; c < HCELLS; c += 256) {
        hb[c] = make_float4(lds[0][c], lds[1][c], lds[2][c], lds[3][c]);
    }
}

// ---------------- grid update: gather halo contributions ----------------
__global__ void __launch_bounds__(256)
grid_kernel(const float4* __restrict__ halo, float4* __restrict__ grid,
            const float* __restrict__ gravity,
            const float* __restrict__ attr_s, const float* __restrict__ attr_p) {
    int g = blockIdx.x * 256 + threadIdx.x;
    if (g >= G3) return;
    int gk = g & (NG-1);
    int gj = (g >> 7) & (NG-1);
    int gi = g >> 14;

    // candidate tiles per axis (1 or 2): halo of tile t covers cells t*8 .. t*8+9
    int tis[2], cis[2], tjs[2], cjs[2], tks[2], cks[2];
    int ni = 1, nj = 1, nk = 1;
    tis[0] = gi >> 3; cis[0] = gi & 7;
    if ((gi & 7) < 2 && (gi >> 3) > 0) { tis[1] = (gi>>3)-1; cis[1] = (gi&7)+8; ni = 2; }
    tjs[0] = gj >> 3; cjs[0] = gj & 7;
    if ((gj & 7) < 2 && (gj >> 3) > 0) { tjs[1] = (gj>>3)-1; cjs[1] = (gj&7)+8; nj = 2; }
    tks[0] = gk >> 3; cks[0] = gk & 7;
    if ((gk & 7) < 2 && (gk >> 3) > 0) { tks[1] = (gk>>3)-1; cks[1] = (gk&7)+8; nk = 2; }

    float mx = 0.f, my = 0.f, mz = 0.f, m = 0.f;
    for (int a = 0; a < ni; ++a)
        for (int b = 0; b < nj; ++b)
            for (int c = 0; c < nk; ++c) {
                int tile = (tis[a]*NT + tjs[b])*NT + tks[c];
                int cell = (cis[a]*10 + cjs[b])*10 + cks[c];
                float4 hv = halo[(size_t)tile*HCELLS + cell];
                mx += hv.x; my += hv.y; mz += hv.z; m += hv.w;
            }

    float gvx = 0.f, gvy = 0.f, gvz = 0.f;
    if (m > 0.f) {
        float inv = 1.0f/m;
        gvx = mx*inv; gvy = my*inv; gvz = mz*inv;
        gvx += DT * gravity[0] * 30.0f;
        gvy += DT * gravity[1] * 30.0f;
        gvz += DT * gravity[2] * 30.0f;
        float dx_ = attr_p[0] - c_DX*(float)gi;
        float dy_ = attr_p[1] - c_DX*(float)gj;
        float dz_ = attr_p[2] - c_DX*(float)gk;
        float nrm = sqrtf(dx_*dx_ + dy_*dy_ + dz_*dz_);
        float sc = attr_s[0] * DT * 100.0f / (0.01f + nrm);
        gvx += dx_*sc; gvy += dy_*sc; gvz += dz_*sc;
        if (gi < 3      && gvx < 0.f) gvx = 0.f;
        if (gi > NG-3   && gvx > 0.f) gvx = 0.f;
        if (gj < 3      && gvy < 0.f) gvy = 0.f;
        if (gj > NG-3   && gvy > 0.f) gvy = 0.f;
        // z unconstrained (matches reference)
    }
    grid[g] = make_float4(gvx, gvy, gvz, m);
}

// ---------------- G2P (sorted order, coalesced record reads) ----------------
__global__ void __launch_bounds__(256)
g2p_kernel(const PRec* __restrict__ rec, const float4* __restrict__ grid,
           float* __restrict__ out, int N) {
    int gid = blockIdx.x * 256 + threadIdx.x;
    if (gid >= N) return;

    float4 r0 = rec[gid].r0;
    float px = r0.x, py = r0.y, pz = r0.z;
    int n = __float_as_int(r0.w);

    int bi, bj, bk; float fx0, fx1, fx2;
    particle_base(px, py, pz, bi, bj, bk, fx0, fx1, fx2);

    float wx[3], wy[3];
    wx[0] = 0.5f*(1.5f-fx0)*(1.5f-fx0); wx[1] = 0.75f-(fx0-1.f)*(fx0-1.f); wx[2] = 0.5f*(fx0-0.5f)*(fx0-0.5f);
    wy[0] = 0.5f*(1.5f-fx1)*(1.5f-fx1); wy[1] = 0.75f-(fx1-1.f)*(fx1-1.f); wy[2] = 0.5f*(fx1-0.5f)*(fx1-0.5f);

    float nvx = 0.f, nvy = 0.f, nvz = 0.f;
    float nC[9];
    #pragma unroll
    for (int i = 0; i < 9; ++i) nC[i] = 0.f;

    #pragma unroll
    for (int i = 0; i < 3; ++i) {
        float dpx = (float)i - fx0;
        #pragma unroll
        for (int j = 0; j < 3; ++j) {
            float wgt = wx[i]*wy[j];
            float dpy = (float)j - fx1;
            int cell0 = ((bi+i)*NG + (bj+j))*NG + bk;
            #pragma unroll
            for (int k = 0; k < 3; ++k) {
                float dpz = (float)k - fx2;
                float4 gv = grid[cell0 + k];
                float wgx = wgt*gv.x, wgy = wgt*gv.y, wgz = wgt*gv.z;
                nvx += wgx; nvy += wgy; nvz += wgz;
                nC[0] += wgx*dpx; nC[1] += wgx*dpy; nC[2] += wgx*dpz;
                nC[3] += wgy*dpx; nC[4] += wgy*dpy; nC[5] += wgy*dpz;
                nC[6] += wgz*dpx; nC[7] += wgz*dpy; nC[8] += wgz*dpz;
            }
        }
    }

    float* po = out + (size_t)n*25;
    po[0] = px + DT*nvx;
    po[1] = py + DT*nvy;
    po[2] = pz + DT*nvz;
    po[3] = nvx; po[4] = nvy; po[5] = nvz;
    float s4 = 4.0f*c_INV_DX;
    #pragma unroll
    for (int i = 0; i < 9; ++i) po[16+i] = s4*nC[i];
}

extern "C" void kernel_launch(void* const* d_in, const int* in_sizes, int n_in,
                              void* d_out, int out_size, void* d_ws, size_t ws_size,
                              hipStream_t stream) {
    const float* x        = (const float*)d_in[0];
    const float* v        = (const float*)d_in[1];
    const float* C        = (const float*)d_in[2];
    const float* F        = (const float*)d_in[3];
    const float* Jp       = (const float*)d_in[4];
    const float* gravity  = (const float*)d_in[5];
    const float* attr_s   = (const float*)d_in[6];
    const float* attr_p   = (const float*)d_in[7];
    const int*   material = (const int*)d_in[8];
    float* out = (float*)d_out;
    int N = in_sizes[0] / 3;

    // workspace layout: [tile_count][cursor] (zeroed) [tile_offset][grid][halo][records]
    char* ws = (char*)d_ws;
    size_t o = 0;
    int* tile_count   = (int*)(ws + o);                    o += NTILES*sizeof(int);
    int* cursor       = (int*)(ws + o);                    o += NTILES*sizeof(int);
    size_t zero_bytes = o;                                 // only the two counter arrays
    int* tile_offset  = (int*)(ws + o);                    o += (NTILES+1)*sizeof(int);
    o = (o + 127) & ~(size_t)127;
    float4* grid      = (float4*)(ws + o);                 o += (size_t)G3*sizeof(float4);
    float4* halo      = (float4*)(ws + o);                 o += (size_t)NTILES*HCELLS*sizeof(float4);
    PRec* rec         = (PRec*)(ws + o);                   o += (size_t)N*sizeof(PRec);

    hipMemsetAsync(d_ws, 0, zero_bytes, stream);

    int pblocks = (N + 255) / 256;
    count_kernel<<<pblocks, 256, 0, stream>>>(x, tile_count, N);
    scan_kernel<<<1, 256, 0, stream>>>(tile_count, tile_offset);
    pre_kernel<<<pblocks, 256, 0, stream>>>(x, v, C, F, Jp, material,
                                            tile_offset, cursor, rec, out, N);
    p2g_tile_kernel<<<NTILES, 256, 0, stream>>>(rec, tile_offset, halo);
    grid_kernel<<<(G3+255)/256, 256, 0, stream>>>(halo, grid, gravity, attr_s, attr_p);
    g2p_kernel<<<pblocks, 256, 0, stream>>>(rec, grid, out, N);
}

// Round 5
// 555.619 us; speedup vs baseline: 1.0025x; 1.0025x over previous
//
#include <hip/hip_runtime.h>

#define NG 128
#define G3 (NG*NG*NG)
#define NT 16               // tiles per axis (8 cells per tile)
#define NTILES (NT*NT*NT)   // 4096
#define HCELLS 1000         // 10x10x10 halo cells per tile

__device__ __constant__ const float c_DX      = 1.0f/128.0f;
__device__ __constant__ const float c_INV_DX  = 128.0f;

#define DT      1e-4f
#define P_VOL   ((1.0f/256.0f)*(1.0f/256.0f))
#define P_MASS  P_VOL
#define MU0     (5000.0f/(2.0f*1.2f))
#define LAM0    (5000.0f*0.2f/(1.2f*0.6f))

// Fast LDS float atomic: native ds_add_f32 (atomicAdd on float compiles to a
// CAS loop without -munsafe-fp-atomics => ~4.7 cyc/lane serialized, the R2-R4
// 330us wall). unsafeAtomicAdd emits the native op.
__device__ inline void lds_fadd(float* p, float v) {
    unsafeAtomicAdd(p, v);
}

// 64-byte packed particle record, written in sorted (tile-bucketed) order
// r0 = {px, py, pz, particle_id}
// r1 = {aff0..3}, r2 = {aff4..7}, r3 = {aff8, mv0, mv1, mv2}
struct __align__(16) PRec {
    float4 r0, r1, r2, r3;
};

// ---------------- 3x3 SVD via Jacobi on A^T A ----------------
__device__ inline void jacobi_rot(float S[3][3], float V[3][3], int p, int q) {
    float apq = S[p][q];
    if (fabsf(apq) < 1e-24f) return;
    float tau = (S[q][q] - S[p][p]) / (2.0f * apq);
    float t = copysignf(1.0f, tau) / (fabsf(tau) + sqrtf(1.0f + tau*tau));
    float c = rsqrtf(1.0f + t*t);
    float sn = t * c;
    #pragma unroll
    for (int k = 0; k < 3; ++k) {
        float Spk = S[p][k], Sqk = S[q][k];
        S[p][k] = c*Spk - sn*Sqk;
        S[q][k] = sn*Spk + c*Sqk;
    }
    #pragma unroll
    for (int k = 0; k < 3; ++k) {
        float Skp = S[k][p], Skq = S[k][q];
        S[k][p] = c*Skp - sn*Skq;
        S[k][q] = sn*Skp + c*Skq;
    }
    #pragma unroll
    for (int k = 0; k < 3; ++k) {
        float Vkp = V[k][p], Vkq = V[k][q];
        V[k][p] = c*Vkp - sn*Vkq;
        V[k][q] = sn*Vkp + c*Vkq;
    }
}

__device__ inline void svd3(const float A[9], float U[9], float sv[3], float V[9]) {
    float S[3][3];
    #pragma unroll
    for (int i = 0; i < 3; ++i)
        #pragma unroll
        for (int j = 0; j < 3; ++j) {
            float acc = 0.f;
            #pragma unroll
            for (int k = 0; k < 3; ++k) acc += A[k*3+i]*A[k*3+j];
            S[i][j] = acc;
        }
    float Vm[3][3] = {{1.f,0.f,0.f},{0.f,1.f,0.f},{0.f,0.f,1.f}};
    #pragma unroll
    for (int sweep = 0; sweep < 4; ++sweep) {
        jacobi_rot(S, Vm, 0, 1);
        jacobi_rot(S, Vm, 0, 2);
        jacobi_rot(S, Vm, 1, 2);
    }
    float lam[3] = {S[0][0], S[1][1], S[2][2]};
    int i0 = 0, i1 = 1, i2 = 2, t;
    if (lam[i0] < lam[i1]) { t = i0; i0 = i1; i1 = t; }
    if (lam[i0] < lam[i2]) { t = i0; i0 = i2; i2 = t; }
    if (lam[i1] < lam[i2]) { t = i1; i1 = i2; i2 = t; }
    int ord[3] = {i0, i1, i2};
    #pragma unroll
    for (int c = 0; c < 3; ++c) {
        int s_ = ord[c];
        float l = fmaxf(lam[s_], 0.f);
        float sval = sqrtf(l);
        sv[c] = sval;
        float v0 = Vm[0][s_], v1 = Vm[1][s_], v2 = Vm[2][s_];
        V[0*3+c] = v0; V[1*3+c] = v1; V[2*3+c] = v2;
        float inv = (sval > 1e-12f) ? 1.0f/sval : 0.f;
        U[0*3+c] = (A[0]*v0 + A[1]*v1 + A[2]*v2)*inv;
        U[1*3+c] = (A[3]*v0 + A[4]*v1 + A[5]*v2)*inv;
        U[2*3+c] = (A[6]*v0 + A[7]*v1 + A[8]*v2)*inv;
    }
}

// ---------------- binning helpers ----------------
__device__ inline void particle_base(float px, float py, float pz,
                                     int& bi, int& bj, int& bk,
                                     float& fx0, float& fx1, float& fx2) {
    float bxf = floorf(px*c_INV_DX - 0.5f);
    float byf = floorf(py*c_INV_DX - 0.5f);
    float bzf = floorf(pz*c_INV_DX - 0.5f);
    bi = (int)bxf; bj = (int)byf; bk = (int)bzf;
    bi = min(max(bi, 0), NG-3); bj = min(max(bj, 0), NG-3); bk = min(max(bk, 0), NG-3);
    fx0 = px*c_INV_DX - bxf;
    fx1 = py*c_INV_DX - byf;
    fx2 = pz*c_INV_DX - bzf;
}

__global__ void __launch_bounds__(256)
count_kernel(const float* __restrict__ x, int* __restrict__ tile_count, int N) {
    int n = blockIdx.x*256 + threadIdx.x;
    if (n >= N) return;
    int bi, bj, bk; float f0, f1, f2;
    particle_base(x[3*n+0], x[3*n+1], x[3*n+2], bi, bj, bk, f0, f1, f2);
    int tile = ((bi >> 3)*NT + (bj >> 3))*NT + (bk >> 3);
    atomicAdd(&tile_count[tile], 1);
}

// exclusive scan of 4096 tile counts, single block of 256 threads x 16 elems
__global__ void __launch_bounds__(256)
scan_kernel(const int* __restrict__ count, int* __restrict__ offset) {
    __shared__ int part[256];
    int t = threadIdx.x;
    int base = t*16;
    int local[16];
    int s = 0;
    #pragma unroll
    for (int i = 0; i < 16; ++i) { local[i] = s; s += count[base+i]; }
    part[t] = s;
    __syncthreads();
    for (int off = 1; off < 256; off <<= 1) {
        int v = (t >= off) ? part[t-off] : 0;
        __syncthreads();
        part[t] += v;
        __syncthreads();
    }
    int prev = (t == 0) ? 0 : part[t-1];
    #pragma unroll
    for (int i = 0; i < 16; ++i) offset[base+i] = prev + local[i];
    if (t == 255) offset[NTILES] = prev + s;
}

// ---------------- pre-pass: all per-particle math, coalesced reads ----------------
__global__ void __launch_bounds__(256)
pre_kernel(const float* __restrict__ x, const float* __restrict__ v,
           const float* __restrict__ Cin, const float* __restrict__ Fin,
           const float* __restrict__ Jp_in, const int* __restrict__ material,
           const int* __restrict__ offset, int* __restrict__ cursor,
           PRec* __restrict__ rec, float* __restrict__ out, int N) {
    int n = blockIdx.x*256 + threadIdx.x;
    if (n >= N) return;

    float px = x[3*n+0], py = x[3*n+1], pz = x[3*n+2];
    int bi, bj, bk; float f0, f1, f2;
    particle_base(px, py, pz, bi, bj, bk, f0, f1, f2);

    float Cm[9], Fm[9];
    #pragma unroll
    for (int i = 0; i < 9; ++i) { Cm[i] = Cin[9*n+i]; Fm[i] = Fin[9*n+i]; }

    // Fn = (I + DT*C) @ F
    float Fn[9];
    #pragma unroll
    for (int i = 0; i < 3; ++i)
        #pragma unroll
        for (int k = 0; k < 3; ++k) {
            float acc = Fm[i*3+k];
            #pragma unroll
            for (int j = 0; j < 3; ++j) acc += DT * Cm[i*3+j] * Fm[j*3+k];
            Fn[i*3+k] = acc;
        }

    float Jp = Jp_in[n];
    int mat = material[n];
    float h = expf(10.0f*(1.0f - Jp));
    h = fminf(fmaxf(h, 0.1f), 5.0f);
    if (mat == 1) h = 0.3f;
    float mu = (mat == 0) ? 0.0f : MU0*h;
    float la = LAM0*h;

    float U[9], V[9], sv[3];
    svd3(Fn, U, sv, V);

    float J = 1.0f;
    float sig[3];
    #pragma unroll
    for (int d = 0; d < 2; ++d) {
        float s = sv[d];
        float ns = (mat == 2) ? fminf(fmaxf(s, 1.0f-0.025f), 1.0f+0.0045f) : s;
        Jp = Jp * s / ns;
        sig[d] = ns;
        J *= ns;
    }
    sig[2] = sv[2];

    if (mat == 0) {
        float sj = sqrtf(J);
        Fn[0]=sj; Fn[1]=0; Fn[2]=0; Fn[3]=0; Fn[4]=sj; Fn[5]=0; Fn[6]=0; Fn[7]=0; Fn[8]=sj;
    } else if (mat == 2) {
        #pragma unroll
        for (int i = 0; i < 3; ++i)
            #pragma unroll
            for (int k = 0; k < 3; ++k) {
                float acc = 0.f;
                #pragma unroll
                for (int j = 0; j < 3; ++j) acc += U[i*3+j]*sig[j]*V[k*3+j];
                Fn[i*3+k] = acc;
            }
    }

    float R[9];
    #pragma unroll
    for (int i = 0; i < 3; ++i)
        #pragma unroll
        for (int k = 0; k < 3; ++k) {
            float acc = 0.f;
            #pragma unroll
            for (int j = 0; j < 3; ++j) acc += U[i*3+j]*V[k*3+j];
            R[i*3+k] = acc;
        }

    float press = la * J * (J - 1.0f);
    float scale = -DT * P_VOL * 4.0f * c_INV_DX * c_INV_DX;
    float aff[9];
    #pragma unroll
    for (int i = 0; i < 3; ++i)
        #pragma unroll
        for (int k = 0; k < 3; ++k) {
            float acc = 0.f;
            #pragma unroll
            for (int j = 0; j < 3; ++j) acc += (Fn[i*3+j]-R[i*3+j])*Fn[k*3+j];
            acc = 2.0f*mu*acc;
            if (i == k) acc += press;
            aff[i*3+k] = scale*acc + P_MASS*Cm[i*3+k];
        }

    float* po = out + (size_t)n*25;
    po[6] = Jp;
    #pragma unroll
    for (int i = 0; i < 9; ++i) po[7+i] = Fn[i];

    // sorted slot
    int tile = ((bi >> 3)*NT + (bj >> 3))*NT + (bk >> 3);
    int pos = offset[tile] + atomicAdd(&cursor[tile], 1);

    // one full 64-B line, written with 4x float4
    float4* rp = (float4*)&rec[pos];
    float4 r0; r0.x = px; r0.y = py; r0.z = pz; r0.w = __int_as_float(n);
    rp[0] = r0;
    rp[1] = make_float4(aff[0], aff[1], aff[2], aff[3]);
    rp[2] = make_float4(aff[4], aff[5], aff[6], aff[7]);
    rp[3] = make_float4(aff[8], P_MASS*v[3*n+0], P_MASS*v[3*n+1], P_MASS*v[3*n+2]);
}

// ---------------- P2G: LDS accumulate -> private halo buffer (no atomics) ------
__global__ void __launch_bounds__(256)
p2g_tile_kernel(const PRec* __restrict__ rec, const int* __restrict__ offset,
                float4* __restrict__ halo) {
    int tile = blockIdx.x;
    int beg = offset[tile], end = offset[tile+1];

    __shared__ float lds[4][HCELLS];   // SoA: [comp][10*10*10 halo cells]
    for (int c = threadIdx.x; c < HCELLS; c += 256) {
        lds[0][c] = 0.f; lds[1][c] = 0.f; lds[2][c] = 0.f; lds[3][c] = 0.f;
    }
    __syncthreads();

    int tx8 = (tile / (NT*NT)) << 3;
    int ty8 = ((tile / NT) % NT) << 3;
    int tz8 = (tile % NT) << 3;

    for (int p = beg + (int)threadIdx.x; p < end; p += 256) {
        const float4* rp = (const float4*)&rec[p];
        float4 r0 = rp[0];
        float4 r1 = rp[1];
        float4 r2 = rp[2];
        float4 r3 = rp[3];

        int bi, bj, bk; float fx0, fx1, fx2;
        particle_base(r0.x, r0.y, r0.z, bi, bj, bk, fx0, fx1, fx2);

        float wx[3], wy[3];
        wx[0] = 0.5f*(1.5f-fx0)*(1.5f-fx0); wx[1] = 0.75f-(fx0-1.f)*(fx0-1.f); wx[2] = 0.5f*(fx0-0.5f)*(fx0-0.5f);
        wy[0] = 0.5f*(1.5f-fx1)*(1.5f-fx1); wy[1] = 0.75f-(fx1-1.f)*(fx1-1.f); wy[2] = 0.5f*(fx1-0.5f)*(fx1-0.5f);

        float a0 = r1.x, a1 = r1.y, a2 = r1.z, a3 = r1.w;
        float a4 = r2.x, a5 = r2.y, a6 = r2.z, a7 = r2.w;
        float a8 = r3.x, mv0 = r3.y, mv1 = r3.z, mv2 = r3.w;

        int offi = bi - tx8, offj = bj - ty8, offk = bk - tz8;
        #pragma unroll
        for (int i = 0; i < 3; ++i) {
            float dpx = ((float)i - fx0)*c_DX;
            #pragma unroll
            for (int j = 0; j < 3; ++j) {
                float wgt = wx[i]*wy[j];     // reference uses only x,y weight factors
                float dpy = ((float)j - fx1)*c_DX;
                int c0 = ((offi+i)*10 + (offj+j))*10 + offk;
                float wm = wgt*P_MASS;
                #pragma unroll
                for (int k = 0; k < 3; ++k) {
                    float dpz = ((float)k - fx2)*c_DX;
                    float mx = wgt*(mv0 + a0*dpx + a1*dpy + a2*dpz);
                    float my = wgt*(mv1 + a3*dpx + a4*dpy + a5*dpz);
                    float mz = wgt*(mv2 + a6*dpx + a7*dpy + a8*dpz);
                    int c = c0 + k;
                    lds_fadd(&lds[0][c], mx);
                    lds_fadd(&lds[1][c], my);
                    lds_fadd(&lds[2][c], mz);
                    lds_fadd(&lds[3][c], wm);
                }
            }
        }
    }
    __syncthreads();

    // dense flush: plain coalesced float4 stores, every tile writes all cells
    float4* hb = halo + (size_t)tile * HCELLS;
    for (int c = threadIdx.x; c < HCELLS; c += 256) {
        hb[c] = make_float4(lds[0][c], lds[1][c], lds[2][c], lds[3][c]);
    }
}

// ---------------- grid update: gather halo contributions ----------------
__global__ void __launch_bounds__(256)
grid_kernel(const float4* __restrict__ halo, float4* __restrict__ grid,
            const float* __restrict__ gravity,
            const float* __restrict__ attr_s, const float* __restrict__ attr_p) {
    int g = blockIdx.x * 256 + threadIdx.x;
    if (g >= G3) return;
    int gk = g & (NG-1);
    int gj = (g >> 7) & (NG-1);
    int gi = g >> 14;

    // candidate tiles per axis (1 or 2): halo of tile t covers cells t*8 .. t*8+9
    int tis[2], cis[2], tjs[2], cjs[2], tks[2], cks[2];
    int ni = 1, nj = 1, nk = 1;
    tis[0] = gi >> 3; cis[0] = gi & 7;
    if ((gi & 7) < 2 && (gi >> 3) > 0) { tis[1] = (gi>>3)-1; cis[1] = (gi&7)+8; ni = 2; }
    tjs[0] = gj >> 3; cjs[0] = gj & 7;
    if ((gj & 7) < 2 && (gj >> 3) > 0) { tjs[1] = (gj>>3)-1; cjs[1] = (gj&7)+8; nj = 2; }
    tks[0] = gk >> 3; cks[0] = gk & 7;
    if ((gk & 7) < 2 && (gk >> 3) > 0) { tks[1] = (gk>>3)-1; cks[1] = (gk&7)+8; nk = 2; }

    float mx = 0.f, my = 0.f, mz = 0.f, m = 0.f;
    for (int a = 0; a < ni; ++a)
        for (int b = 0; b < nj; ++b)
            for (int c = 0; c < nk; ++c) {
                int tile = (tis[a]*NT + tjs[b])*NT + tks[c];
                int cell = (cis[a]*10 + cjs[b])*10 + cks[c];
                float4 hv = halo[(size_t)tile*HCELLS + cell];
                mx += hv.x; my += hv.y; mz += hv.z; m += hv.w;
            }

    float gvx = 0.f, gvy = 0.f, gvz = 0.f;
    if (m > 0.f) {
        float inv = 1.0f/m;
        gvx = mx*inv; gvy = my*inv; gvz = mz*inv;
        gvx += DT * gravity[0] * 30.0f;
        gvy += DT * gravity[1] * 30.0f;
        gvz += DT * gravity[2] * 30.0f;
        float dx_ = attr_p[0] - c_DX*(float)gi;
        float dy_ = attr_p[1] - c_DX*(float)gj;
        float dz_ = attr_p[2] - c_DX*(float)gk;
        float nrm = sqrtf(dx_*dx_ + dy_*dy_ + dz_*dz_);
        float sc = attr_s[0] * DT * 100.0f / (0.01f + nrm);
        gvx += dx_*sc; gvy += dy_*sc; gvz += dz_*sc;
        if (gi < 3      && gvx < 0.f) gvx = 0.f;
        if (gi > NG-3   && gvx > 0.f) gvx = 0.f;
        if (gj < 3      && gvy < 0.f) gvy = 0.f;
        if (gj > NG-3   && gvy > 0.f) gvy = 0.f;
        // z unconstrained (matches reference)
    }
    grid[g] = make_float4(gvx, gvy, gvz, m);
}

// ---------------- G2P (sorted order, coalesced record reads) ----------------
__global__ void __launch_bounds__(256)
g2p_kernel(const PRec* __restrict__ rec, const float4* __restrict__ grid,
           float* __restrict__ out, int N) {
    int gid = blockIdx.x * 256 + threadIdx.x;
    if (gid >= N) return;

    float4 r0 = rec[gid].r0;
    float px = r0.x, py = r0.y, pz = r0.z;
    int n = __float_as_int(r0.w);

    int bi, bj, bk; float fx0, fx1, fx2;
    particle_base(px, py, pz, bi, bj, bk, fx0, fx1, fx2);

    float wx[3], wy[3];
    wx[0] = 0.5f*(1.5f-fx0)*(1.5f-fx0); wx[1] = 0.75f-(fx0-1.f)*(fx0-1.f); wx[2] = 0.5f*(fx0-0.5f)*(fx0-0.5f);
    wy[0] = 0.5f*(1.5f-fx1)*(1.5f-fx1); wy[1] = 0.75f-(fx1-1.f)*(fx1-1.f); wy[2] = 0.5f*(fx1-0.5f)*(fx1-0.5f);

    float nvx = 0.f, nvy = 0.f, nvz = 0.f;
    float nC[9];
    #pragma unroll
    for (int i = 0; i < 9; ++i) nC[i] = 0.f;

    #pragma unroll
    for (int i = 0; i < 3; ++i) {
        float dpx = (float)i - fx0;
        #pragma unroll
        for (int j = 0; j < 3; ++j) {
            float wgt = wx[i]*wy[j];
            float dpy = (float)j - fx1;
            int cell0 = ((bi+i)*NG + (bj+j))*NG + bk;
            #pragma unroll
            for (int k = 0; k < 3; ++k) {
                float dpz = (float)k - fx2;
                float4 gv = grid[cell0 + k];
                float wgx = wgt*gv.x, wgy = wgt*gv.y, wgz = wgt*gv.z;
                nvx += wgx; nvy += wgy; nvz += wgz;
                nC[0] += wgx*dpx; nC[1] += wgx*dpy; nC[2] += wgx*dpz;
                nC[3] += wgy*dpx; nC[4] += wgy*dpy; nC[5] += wgy*dpz;
                nC[6] += wgz*dpx; nC[7] += wgz*dpy; nC[8] += wgz*dpz;
            }
        }
    }

    float* po = out + (size_t)n*25;
    po[0] = px + DT*nvx;
    po[1] = py + DT*nvy;
    po[2] = pz + DT*nvz;
    po[3] = nvx; po[4] = nvy; po[5] = nvz;
    float s4 = 4.0f*c_INV_DX;
    #pragma unroll
    for (int i = 0; i < 9; ++i) po[16+i] = s4*nC[i];
}

extern "C" void kernel_launch(void* const* d_in, const int* in_sizes, int n_in,
                              void* d_out, int out_size, void* d_ws, size_t ws_size,
                              hipStream_t stream) {
    const float* x        = (const float*)d_in[0];
    const float* v        = (const float*)d_in[1];
    const float* C        = (const float*)d_in[2];
    const float* F        = (const float*)d_in[3];
    const float* Jp       = (const float*)d_in[4];
    const float* gravity  = (const float*)d_in[5];
    const float* attr_s   = (const float*)d_in[6];
    const float* attr_p   = (const float*)d_in[7];
    const int*   material = (const int*)d_in[8];
    float* out = (float*)d_out;
    int N = in_sizes[0] / 3;

    // workspace layout: [tile_count][cursor] (zeroed) [tile_offset][grid][halo][records]
    char* ws = (char*)d_ws;
    size_t o = 0;
    int* tile_count   = (int*)(ws + o);                    o += NTILES*sizeof(int);
    int* cursor       = (int*)(ws + o);                    o += NTILES*sizeof(int);
    size_t zero_bytes = o;                                 // only the two counter arrays
    int* tile_offset  = (int*)(ws + o);                    o += (NTILES+1)*sizeof(int);
    o = (o + 127) & ~(size_t)127;
    float4* grid      = (float4*)(ws + o);                 o += (size_t)G3*sizeof(float4);
    float4* halo      = (float4*)(ws + o);                 o += (size_t)NTILES*HCELLS*sizeof(float4);
    PRec* rec         = (PRec*)(ws + o);                   o += (size_t)N*sizeof(PRec);

    hipMemsetAsync(d_ws, 0, zero_bytes, stream);

    int pblocks = (N + 255) / 256;
    count_kernel<<<pblocks, 256, 0, stream>>>(x, tile_count, N);
    scan_kernel<<<1, 256, 0, stream>>>(tile_count, tile_offset);
    pre_kernel<<<pblocks, 256, 0, stream>>>(x, v, C, F, Jp, material,
                                            tile_offset, cursor, rec, out, N);
    p2g_tile_kernel<<<NTILES, 256, 0, stream>>>(rec, tile_offset, halo);
    grid_kernel<<<(G3+255)/256, 256, 0, stream>>>(halo, grid, gravity, attr_s, attr_p);
    g2p_kernel<<<pblocks, 256, 0, stream>>>(rec, grid, out, N);
}

// Round 6
// 321.332 us; speedup vs baseline: 1.7335x; 1.7291x over previous
//
#include <hip/hip_runtime.h>

#define NG 128
#define G3 (NG*NG*NG)
#define NSCAN_BLOCKS (G3/256)   // 8192

__device__ __constant__ const float c_DX      = 1.0f/128.0f;
__device__ __constant__ const float c_INV_DX  = 128.0f;

#define DT      1e-4f
#define P_VOL   ((1.0f/256.0f)*(1.0f/256.0f))
#define P_MASS  P_VOL
#define MU0     (5000.0f/(2.0f*1.2f))
#define LAM0    (5000.0f*0.2f/(1.2f*0.6f))

// 64-byte packed particle record, stored in cell-bucket order
// r0 = {px, py, pz, particle_id}
// r1 = {aff0..3}, r2 = {aff4..7}, r3 = {aff8, mv0, mv1, mv2}
struct __align__(16) PRec {
    float4 r0, r1, r2, r3;
};

// ---------------- 3x3 SVD via Jacobi on A^T A ----------------
__device__ inline void jacobi_rot(float S[3][3], float V[3][3], int p, int q) {
    float apq = S[p][q];
    if (fabsf(apq) < 1e-24f) return;
    float tau = (S[q][q] - S[p][p]) / (2.0f * apq);
    float t = copysignf(1.0f, tau) / (fabsf(tau) + sqrtf(1.0f + tau*tau));
    float c = rsqrtf(1.0f + t*t);
    float sn = t * c;
    #pragma unroll
    for (int k = 0; k < 3; ++k) {
        float Spk = S[p][k], Sqk = S[q][k];
        S[p][k] = c*Spk - sn*Sqk;
        S[q][k] = sn*Spk + c*Sqk;
    }
    #pragma unroll
    for (int k = 0; k < 3; ++k) {
        float Skp = S[k][p], Skq = S[k][q];
        S[k][p] = c*Skp - sn*Skq;
        S[k][q] = sn*Skp + c*Skq;
    }
    #pragma unroll
    for (int k = 0; k < 3; ++k) {
        float Vkp = V[k][p], Vkq = V[k][q];
        V[k][p] = c*Vkp - sn*Vkq;
        V[k][q] = sn*Vkp + c*Vkq;
    }
}

__device__ inline void svd3(const float A[9], float U[9], float sv[3], float V[9]) {
    float S[3][3];
    #pragma unroll
    for (int i = 0; i < 3; ++i)
        #pragma unroll
        for (int j = 0; j < 3; ++j) {
            float acc = 0.f;
            #pragma unroll
            for (int k = 0; k < 3; ++k) acc += A[k*3+i]*A[k*3+j];
            S[i][j] = acc;
        }
    float Vm[3][3] = {{1.f,0.f,0.f},{0.f,1.f,0.f},{0.f,0.f,1.f}};
    #pragma unroll
    for (int sweep = 0; sweep < 4; ++sweep) {
        jacobi_rot(S, Vm, 0, 1);
        jacobi_rot(S, Vm, 0, 2);
        jacobi_rot(S, Vm, 1, 2);
    }
    float lam[3] = {S[0][0], S[1][1], S[2][2]};
    int i0 = 0, i1 = 1, i2 = 2, t;
    if (lam[i0] < lam[i1]) { t = i0; i0 = i1; i1 = t; }
    if (lam[i0] < lam[i2]) { t = i0; i0 = i2; i2 = t; }
    if (lam[i1] < lam[i2]) { t = i1; i1 = i2; i2 = t; }
    int ord[3] = {i0, i1, i2};
    #pragma unroll
    for (int c = 0; c < 3; ++c) {
        int s_ = ord[c];
        float l = fmaxf(lam[s_], 0.f);
        float sval = sqrtf(l);
        sv[c] = sval;
        float v0 = Vm[0][s_], v1 = Vm[1][s_], v2 = Vm[2][s_];
        V[0*3+c] = v0; V[1*3+c] = v1; V[2*3+c] = v2;
        float inv = (sval > 1e-12f) ? 1.0f/sval : 0.f;
        U[0*3+c] = (A[0]*v0 + A[1]*v1 + A[2]*v2)*inv;
        U[1*3+c] = (A[3]*v0 + A[4]*v1 + A[5]*v2)*inv;
        U[2*3+c] = (A[6]*v0 + A[7]*v1 + A[8]*v2)*inv;
    }
}

// ---------------- binning helpers ----------------
__device__ inline void particle_base(float px, float py, float pz,
                                     int& bi, int& bj, int& bk,
                                     float& fx0, float& fx1, float& fx2) {
    float bxf = floorf(px*c_INV_DX - 0.5f);
    float byf = floorf(py*c_INV_DX - 0.5f);
    float bzf = floorf(pz*c_INV_DX - 0.5f);
    bi = (int)bxf; bj = (int)byf; bk = (int)bzf;
    bi = min(max(bi, 0), NG-3); bj = min(max(bj, 0), NG-3); bk = min(max(bk, 0), NG-3);
    fx0 = px*c_INV_DX - bxf;
    fx1 = py*c_INV_DX - byf;
    fx2 = pz*c_INV_DX - bzf;
}

// quadratic B-spline weight for offset o in {0,1,2}
__device__ inline float wsel(int o, float f) {
    float w0 = 0.5f*(1.5f-f)*(1.5f-f);
    float w1 = 0.75f-(f-1.f)*(f-1.f);
    float w2 = 0.5f*(f-0.5f)*(f-0.5f);
    return (o == 0) ? w0 : ((o == 1) ? w1 : w2);
}

__global__ void __launch_bounds__(256)
count_kernel(const float* __restrict__ x, int* __restrict__ cell_count, int N) {
    int n = blockIdx.x*256 + threadIdx.x;
    if (n >= N) return;
    int bi, bj, bk; float f0, f1, f2;
    particle_base(x[3*n+0], x[3*n+1], x[3*n+2], bi, bj, bk, f0, f1, f2);
    atomicAdd(&cell_count[(bi*NG + bj)*NG + bk], 1);
}

// ---- scan stage A: per-block (256 elems) reduction -> partial[block] ----
__global__ void __launch_bounds__(256)
scan_partial_kernel(const int* __restrict__ count, int* __restrict__ partial) {
    __shared__ int red[256];
    int t = threadIdx.x;
    red[t] = count[blockIdx.x*256 + t];
    __syncthreads();
    for (int off = 128; off > 0; off >>= 1) {
        if (t < off) red[t] += red[t+off];
        __syncthreads();
    }
    if (t == 0) partial[blockIdx.x] = red[0];
}

// ---- scan stage B: exclusive scan of 8192 partials, 1 block, 256x32 ----
__global__ void __launch_bounds__(256)
scan_partials_kernel(int* __restrict__ partial) {
    __shared__ int part[256];
    int t = threadIdx.x;
    int base = t*32;
    int local[32];
    int s = 0;
    #pragma unroll
    for (int i = 0; i < 32; ++i) { local[i] = s; s += partial[base+i]; }
    part[t] = s;
    __syncthreads();
    for (int off = 1; off < 256; off <<= 1) {
        int v = (t >= off) ? part[t-off] : 0;
        __syncthreads();
        part[t] += v;
        __syncthreads();
    }
    int prev = (t == 0) ? 0 : part[t-1];
    #pragma unroll
    for (int i = 0; i < 32; ++i) partial[base+i] = prev + local[i];
}

// ---- scan stage C: block-level exclusive scan + partial base -> offset ----
__global__ void __launch_bounds__(256)
scan_final_kernel(const int* __restrict__ count, const int* __restrict__ partial,
                  int* __restrict__ offset) {
    __shared__ int part[256];
    int t = threadIdx.x;
    int i = blockIdx.x*256 + t;
    int c = count[i];
    part[t] = c;
    __syncthreads();
    for (int off = 1; off < 256; off <<= 1) {
        int v = (t >= off) ? part[t-off] : 0;
        __syncthreads();
        part[t] += v;
        __syncthreads();
    }
    int base = partial[blockIdx.x];
    offset[i] = base + part[t] - c;
    if (i == G3-1) offset[G3] = base + part[t];
}

// ---------------- pre-pass: all per-particle math, coalesced reads ----------------
__global__ void __launch_bounds__(256)
pre_kernel(const float* __restrict__ x, const float* __restrict__ v,
           const float* __restrict__ Cin, const float* __restrict__ Fin,
           const float* __restrict__ Jp_in, const int* __restrict__ material,
           const int* __restrict__ offset, int* __restrict__ cursor,
           PRec* __restrict__ rec, float* __restrict__ out, int N) {
    int n = blockIdx.x*256 + threadIdx.x;
    if (n >= N) return;

    float px = x[3*n+0], py = x[3*n+1], pz = x[3*n+2];
    int bi, bj, bk; float f0, f1, f2;
    particle_base(px, py, pz, bi, bj, bk, f0, f1, f2);

    float Cm[9], Fm[9];
    #pragma unroll
    for (int i = 0; i < 9; ++i) { Cm[i] = Cin[9*n+i]; Fm[i] = Fin[9*n+i]; }

    // Fn = (I + DT*C) @ F
    float Fn[9];
    #pragma unroll
    for (int i = 0; i < 3; ++i)
        #pragma unroll
        for (int k = 0; k < 3; ++k) {
            float acc = Fm[i*3+k];
            #pragma unroll
            for (int j = 0; j < 3; ++j) acc += DT * Cm[i*3+j] * Fm[j*3+k];
            Fn[i*3+k] = acc;
        }

    float Jp = Jp_in[n];
    int mat = material[n];
    float h = expf(10.0f*(1.0f - Jp));
    h = fminf(fmaxf(h, 0.1f), 5.0f);
    if (mat == 1) h = 0.3f;
    float mu = (mat == 0) ? 0.0f : MU0*h;
    float la = LAM0*h;

    float U[9], V[9], sv[3];
    svd3(Fn, U, sv, V);

    float J = 1.0f;
    float sig[3];
    #pragma unroll
    for (int d = 0; d < 2; ++d) {
        float s = sv[d];
        float ns = (mat == 2) ? fminf(fmaxf(s, 1.0f-0.025f), 1.0f+0.0045f) : s;
        Jp = Jp * s / ns;
        sig[d] = ns;
        J *= ns;
    }
    sig[2] = sv[2];

    if (mat == 0) {
        float sj = sqrtf(J);
        Fn[0]=sj; Fn[1]=0; Fn[2]=0; Fn[3]=0; Fn[4]=sj; Fn[5]=0; Fn[6]=0; Fn[7]=0; Fn[8]=sj;
    } else if (mat == 2) {
        #pragma unroll
        for (int i = 0; i < 3; ++i)
            #pragma unroll
            for (int k = 0; k < 3; ++k) {
                float acc = 0.f;
                #pragma unroll
                for (int j = 0; j < 3; ++j) acc += U[i*3+j]*sig[j]*V[k*3+j];
                Fn[i*3+k] = acc;
            }
    }

    float R[9];
    #pragma unroll
    for (int i = 0; i < 3; ++i)
        #pragma unroll
        for (int k = 0; k < 3; ++k) {
            float acc = 0.f;
            #pragma unroll
            for (int j = 0; j < 3; ++j) acc += U[i*3+j]*V[k*3+j];
            R[i*3+k] = acc;
        }

    float press = la * J * (J - 1.0f);
    float scale = -DT * P_VOL * 4.0f * c_INV_DX * c_INV_DX;
    float aff[9];
    #pragma unroll
    for (int i = 0; i < 3; ++i)
        #pragma unroll
        for (int k = 0; k < 3; ++k) {
            float acc = 0.f;
            #pragma unroll
            for (int j = 0; j < 3; ++j) acc += (Fn[i*3+j]-R[i*3+j])*Fn[k*3+j];
            acc = 2.0f*mu*acc;
            if (i == k) acc += press;
            aff[i*3+k] = scale*acc + P_MASS*Cm[i*3+k];
        }

    float* po = out + (size_t)n*25;
    po[6] = Jp;
    #pragma unroll
    for (int i = 0; i < 9; ++i) po[7+i] = Fn[i];

    // cell-bucket slot
    int cell = (bi*NG + bj)*NG + bk;
    int pos = offset[cell] + atomicAdd(&cursor[cell], 1);

    float4* rp = (float4*)&rec[pos];
    float4 r0; r0.x = px; r0.y = py; r0.z = pz; r0.w = __int_as_float(n);
    rp[0] = r0;
    rp[1] = make_float4(aff[0], aff[1], aff[2], aff[3]);
    rp[2] = make_float4(aff[4], aff[5], aff[6], aff[7]);
    rp[3] = make_float4(aff[8], P_MASS*v[3*n+0], P_MASS*v[3*n+1], P_MASS*v[3*n+2]);
}

// ------- fused P2G-gather + grid update: one thread per cell, NO atomics -------
__global__ void __launch_bounds__(256)
grid_gather_kernel(const PRec* __restrict__ rec, const int* __restrict__ offset,
                   float4* __restrict__ grid, const float* __restrict__ gravity,
                   const float* __restrict__ attr_s, const float* __restrict__ attr_p) {
    int g = blockIdx.x*256 + threadIdx.x;
    if (g >= G3) return;
    int gk = g & (NG-1);
    int gj = (g >> 7) & (NG-1);
    int gi = g >> 14;

    float mx = 0.f, my = 0.f, mz = 0.f, m = 0.f;

    int bi0 = max(gi-2, 0), bi1 = min(gi, NG-3);
    int bj0 = max(gj-2, 0), bj1 = min(gj, NG-3);
    int bk0 = max(gk-2, 0), bk1 = min(gk, NG-3);

    for (int bi = bi0; bi <= bi1; ++bi) {
        for (int bj = bj0; bj <= bj1; ++bj) {
            int col = (bi*NG + bj)*NG;
            int s = offset[col + bk0];
            int e = offset[col + bk1 + 1];
            for (int p = s; p < e; ++p) {
                const float4* rp = (const float4*)&rec[p];
                float4 r0 = rp[0];
                float4 r1 = rp[1];
                float4 r2 = rp[2];
                float4 r3 = rp[3];
                int pbi, pbj, pbk; float f0, f1, f2;
                particle_base(r0.x, r0.y, r0.z, pbi, pbj, pbk, f0, f1, f2);
                int oi = gi - pbi, oj = gj - pbj, ok = gk - pbk;
                float wgt = wsel(oi, f0) * wsel(oj, f1);   // reference: x,y weights only
                float dpx = ((float)oi - f0)*c_DX;
                float dpy = ((float)oj - f1)*c_DX;
                float dpz = ((float)ok - f2)*c_DX;
                mx += wgt*(r3.y + r1.x*dpx + r1.y*dpy + r1.z*dpz);
                my += wgt*(r3.z + r1.w*dpx + r2.x*dpy + r2.y*dpz);
                mz += wgt*(r3.w + r2.z*dpx + r2.w*dpy + r3.x*dpz);
                m  += wgt*P_MASS;
            }
        }
    }

    float gvx = 0.f, gvy = 0.f, gvz = 0.f;
    if (m > 0.f) {
        float inv = 1.0f/m;
        gvx = mx*inv; gvy = my*inv; gvz = mz*inv;
        gvx += DT * gravity[0] * 30.0f;
        gvy += DT * gravity[1] * 30.0f;
        gvz += DT * gravity[2] * 30.0f;
        float dx_ = attr_p[0] - c_DX*(float)gi;
        float dy_ = attr_p[1] - c_DX*(float)gj;
        float dz_ = attr_p[2] - c_DX*(float)gk;
        float nrm = sqrtf(dx_*dx_ + dy_*dy_ + dz_*dz_);
        float sc = attr_s[0] * DT * 100.0f / (0.01f + nrm);
        gvx += dx_*sc; gvy += dy_*sc; gvz += dz_*sc;
        if (gi < 3      && gvx < 0.f) gvx = 0.f;
        if (gi > NG-3   && gvx > 0.f) gvx = 0.f;
        if (gj < 3      && gvy < 0.f) gvy = 0.f;
        if (gj > NG-3   && gvy > 0.f) gvy = 0.f;
        // z unconstrained (matches reference)
    }
    grid[g] = make_float4(gvx, gvy, gvz, m);
}

// ---------------- G2P (cell-sorted order, coalesced record reads) ----------------
__global__ void __launch_bounds__(256)
g2p_kernel(const PRec* __restrict__ rec, const float4* __restrict__ grid,
           float* __restrict__ out, int N) {
    int gid = blockIdx.x * 256 + threadIdx.x;
    if (gid >= N) return;

    float4 r0 = rec[gid].r0;
    float px = r0.x, py = r0.y, pz = r0.z;
    int n = __float_as_int(r0.w);

    int bi, bj, bk; float fx0, fx1, fx2;
    particle_base(px, py, pz, bi, bj, bk, fx0, fx1, fx2);

    float wx[3], wy[3];
    wx[0] = 0.5f*(1.5f-fx0)*(1.5f-fx0); wx[1] = 0.75f-(fx0-1.f)*(fx0-1.f); wx[2] = 0.5f*(fx0-0.5f)*(fx0-0.5f);
    wy[0] = 0.5f*(1.5f-fx1)*(1.5f-fx1); wy[1] = 0.75f-(fx1-1.f)*(fx1-1.f); wy[2] = 0.5f*(fx1-0.5f)*(fx1-0.5f);

    float nvx = 0.f, nvy = 0.f, nvz = 0.f;
    float nC[9];
    #pragma unroll
    for (int i = 0; i < 9; ++i) nC[i] = 0.f;

    #pragma unroll
    for (int i = 0; i < 3; ++i) {
        float dpx = (float)i - fx0;
        #pragma unroll
        for (int j = 0; j < 3; ++j) {
            float wgt = wx[i]*wy[j];
            float dpy = (float)j - fx1;
            int cell0 = ((bi+i)*NG + (bj+j))*NG + bk;
            #pragma unroll
            for (int k = 0; k < 3; ++k) {
                float dpz = (float)k - fx2;
                float4 gv = grid[cell0 + k];
                float wgx = wgt*gv.x, wgy = wgt*gv.y, wgz = wgt*gv.z;
                nvx += wgx; nvy += wgy; nvz += wgz;
                nC[0] += wgx*dpx; nC[1] += wgx*dpy; nC[2] += wgx*dpz;
                nC[3] += wgy*dpx; nC[4] += wgy*dpy; nC[5] += wgy*dpz;
                nC[6] += wgz*dpx; nC[7] += wgz*dpy; nC[8] += wgz*dpz;
            }
        }
    }

    float* po = out + (size_t)n*25;
    po[0] = px + DT*nvx;
    po[1] = py + DT*nvy;
    po[2] = pz + DT*nvz;
    po[3] = nvx; po[4] = nvy; po[5] = nvz;
    float s4 = 4.0f*c_INV_DX;
    #pragma unroll
    for (int i = 0; i < 9; ++i) po[16+i] = s4*nC[i];
}

extern "C" void kernel_launch(void* const* d_in, const int* in_sizes, int n_in,
                              void* d_out, int out_size, void* d_ws, size_t ws_size,
                              hipStream_t stream) {
    const float* x        = (const float*)d_in[0];
    const float* v        = (const float*)d_in[1];
    const float* C        = (const float*)d_in[2];
    const float* F        = (const float*)d_in[3];
    const float* Jp       = (const float*)d_in[4];
    const float* gravity  = (const float*)d_in[5];
    const float* attr_s   = (const float*)d_in[6];
    const float* attr_p   = (const float*)d_in[7];
    const int*   material = (const int*)d_in[8];
    float* out = (float*)d_out;
    int N = in_sizes[0] / 3;

    // workspace: [count G3][cursor G3] (zeroed) [offset G3+1][partial 8192][grid][rec]
    char* ws = (char*)d_ws;
    size_t o = 0;
    int* cell_count = (int*)(ws + o);      o += (size_t)G3*sizeof(int);
    int* cursor     = (int*)(ws + o);      o += (size_t)G3*sizeof(int);
    size_t zero_bytes = o;
    int* offset     = (int*)(ws + o);      o += ((size_t)G3+1)*sizeof(int);
    int* partial    = (int*)(ws + o);      o += (size_t)NSCAN_BLOCKS*sizeof(int);
    o = (o + 127) & ~(size_t)127;
    float4* grid    = (float4*)(ws + o);   o += (size_t)G3*sizeof(float4);
    PRec* rec       = (PRec*)(ws + o);     o += (size_t)N*sizeof(PRec);

    hipMemsetAsync(d_ws, 0, zero_bytes, stream);

    int pblocks = (N + 255) / 256;
    count_kernel<<<pblocks, 256, 0, stream>>>(x, cell_count, N);
    scan_partial_kernel<<<NSCAN_BLOCKS, 256, 0, stream>>>(cell_count, partial);
    scan_partials_kernel<<<1, 256, 0, stream>>>(partial);
    scan_final_kernel<<<NSCAN_BLOCKS, 256, 0, stream>>>(cell_count, partial, offset);
    pre_kernel<<<pblocks, 256, 0, stream>>>(x, v, C, F, Jp, material,
                                            offset, cursor, rec, out, N);
    grid_gather_kernel<<<G3/256, 256, 0, stream>>>(rec, offset, grid,
                                                   gravity, attr_s, attr_p);
    g2p_kernel<<<pblocks, 256, 0, stream>>>(rec, grid, out, N);
}

// Round 7
// 296.320 us; speedup vs baseline: 1.8798x; 1.0844x over previous
//
#include <hip/hip_runtime.h>

#define NG 128
#define G3 (NG*NG*NG)
#define NSCAN_BLOCKS (G3/256)   // 8192

__device__ __constant__ const float c_DX      = 1.0f/128.0f;
__device__ __constant__ const float c_INV_DX  = 128.0f;

#define DT      1e-4f
#define P_VOL   ((1.0f/256.0f)*(1.0f/256.0f))
#define P_MASS  P_VOL
#define MU0     (5000.0f/(2.0f*1.2f))
#define LAM0    (5000.0f*0.2f/(1.2f*0.6f))

// 64-byte packed particle record, stored in cell-bucket order
// r0 = {A0, A1, A2, particle_id}   A = x*INV_DX (absolute grid coord; exact)
// r1 = {aff0..3}, r2 = {aff4..7}, r3 = {aff8, mv0, mv1, mv2}
struct __align__(16) PRec {
    float4 r0, r1, r2, r3;
};

// ---------------- 3x3 SVD via Jacobi on A^T A ----------------
__device__ inline void jacobi_rot(float S[3][3], float V[3][3], int p, int q) {
    float apq = S[p][q];
    if (fabsf(apq) < 1e-24f) return;
    float tau = (S[q][q] - S[p][p]) / (2.0f * apq);
    float t = copysignf(1.0f, tau) / (fabsf(tau) + sqrtf(1.0f + tau*tau));
    float c = rsqrtf(1.0f + t*t);
    float sn = t * c;
    #pragma unroll
    for (int k = 0; k < 3; ++k) {
        float Spk = S[p][k], Sqk = S[q][k];
        S[p][k] = c*Spk - sn*Sqk;
        S[q][k] = sn*Spk + c*Sqk;
    }
    #pragma unroll
    for (int k = 0; k < 3; ++k) {
        float Skp = S[k][p], Skq = S[k][q];
        S[k][p] = c*Skp - sn*Skq;
        S[k][q] = sn*Skp + c*Skq;
    }
    #pragma unroll
    for (int k = 0; k < 3; ++k) {
        float Vkp = V[k][p], Vkq = V[k][q];
        V[k][p] = c*Vkp - sn*Vkq;
        V[k][q] = sn*Vkp + c*Vkq;
    }
}

__device__ inline void svd3(const float A[9], float U[9], float sv[3], float V[9]) {
    float S[3][3];
    #pragma unroll
    for (int i = 0; i < 3; ++i)
        #pragma unroll
        for (int j = 0; j < 3; ++j) {
            float acc = 0.f;
            #pragma unroll
            for (int k = 0; k < 3; ++k) acc += A[k*3+i]*A[k*3+j];
            S[i][j] = acc;
        }
    float Vm[3][3] = {{1.f,0.f,0.f},{0.f,1.f,0.f},{0.f,0.f,1.f}};
    #pragma unroll
    for (int sweep = 0; sweep < 4; ++sweep) {
        jacobi_rot(S, Vm, 0, 1);
        jacobi_rot(S, Vm, 0, 2);
        jacobi_rot(S, Vm, 1, 2);
    }
    float lam[3] = {S[0][0], S[1][1], S[2][2]};
    int i0 = 0, i1 = 1, i2 = 2, t;
    if (lam[i0] < lam[i1]) { t = i0; i0 = i1; i1 = t; }
    if (lam[i0] < lam[i2]) { t = i0; i0 = i2; i2 = t; }
    if (lam[i1] < lam[i2]) { t = i1; i1 = i2; i2 = t; }
    int ord[3] = {i0, i1, i2};
    #pragma unroll
    for (int c = 0; c < 3; ++c) {
        int s_ = ord[c];
        float l = fmaxf(lam[s_], 0.f);
        float sval = sqrtf(l);
        sv[c] = sval;
        float v0 = Vm[0][s_], v1 = Vm[1][s_], v2 = Vm[2][s_];
        V[0*3+c] = v0; V[1*3+c] = v1; V[2*3+c] = v2;
        float inv = (sval > 1e-12f) ? 1.0f/sval : 0.f;
        U[0*3+c] = (A[0]*v0 + A[1]*v1 + A[2]*v2)*inv;
        U[1*3+c] = (A[3]*v0 + A[4]*v1 + A[5]*v2)*inv;
        U[2*3+c] = (A[6]*v0 + A[7]*v1 + A[8]*v2)*inv;
    }
}

// ---------------- binning helpers ----------------
// from absolute grid coord A: base cell + frac (all fp-exact)
__device__ inline void base_from_A(float A0, float A1, float A2,
                                   int& bi, int& bj, int& bk,
                                   float& fx0, float& fx1, float& fx2) {
    float bxf = floorf(A0 - 0.5f);
    float byf = floorf(A1 - 0.5f);
    float bzf = floorf(A2 - 0.5f);
    bi = (int)bxf; bj = (int)byf; bk = (int)bzf;
    bi = min(max(bi, 0), NG-3); bj = min(max(bj, 0), NG-3); bk = min(max(bk, 0), NG-3);
    fx0 = A0 - bxf;
    fx1 = A1 - byf;
    fx2 = A2 - bzf;
}

__global__ void __launch_bounds__(256)
count_kernel(const float* __restrict__ x, int* __restrict__ cell_count, int N) {
    int n = blockIdx.x*256 + threadIdx.x;
    if (n >= N) return;
    int bi, bj, bk; float f0, f1, f2;
    base_from_A(x[3*n+0]*c_INV_DX, x[3*n+1]*c_INV_DX, x[3*n+2]*c_INV_DX,
                bi, bj, bk, f0, f1, f2);
    atomicAdd(&cell_count[(bi*NG + bj)*NG + bk], 1);
}

// ---- scan stage A: per-block (256 elems) reduction -> partial[block] ----
__global__ void __launch_bounds__(256)
scan_partial_kernel(const int* __restrict__ count, int* __restrict__ partial) {
    __shared__ int red[256];
    int t = threadIdx.x;
    red[t] = count[blockIdx.x*256 + t];
    __syncthreads();
    for (int off = 128; off > 0; off >>= 1) {
        if (t < off) red[t] += red[t+off];
        __syncthreads();
    }
    if (t == 0) partial[blockIdx.x] = red[0];
}

// ---- scan stage B: exclusive scan of 8192 partials, 1 block, 256x32 ----
__global__ void __launch_bounds__(256)
scan_partials_kernel(int* __restrict__ partial) {
    __shared__ int part[256];
    int t = threadIdx.x;
    int base = t*32;
    int local[32];
    int s = 0;
    #pragma unroll
    for (int i = 0; i < 32; ++i) { local[i] = s; s += partial[base+i]; }
    part[t] = s;
    __syncthreads();
    for (int off = 1; off < 256; off <<= 1) {
        int v = (t >= off) ? part[t-off] : 0;
        __syncthreads();
        part[t] += v;
        __syncthreads();
    }
    int prev = (t == 0) ? 0 : part[t-1];
    #pragma unroll
    for (int i = 0; i < 32; ++i) partial[base+i] = prev + local[i];
}

// ---- scan stage C: block-level exclusive scan + partial base -> offset ----
__global__ void __launch_bounds__(256)
scan_final_kernel(const int* __restrict__ count, const int* __restrict__ partial,
                  int* __restrict__ offset) {
    __shared__ int part[256];
    int t = threadIdx.x;
    int i = blockIdx.x*256 + t;
    int c = count[i];
    part[t] = c;
    __syncthreads();
    for (int off = 1; off < 256; off <<= 1) {
        int v = (t >= off) ? part[t-off] : 0;
        __syncthreads();
        part[t] += v;
        __syncthreads();
    }
    int base = partial[blockIdx.x];
    offset[i] = base + part[t] - c;
    if (i == G3-1) offset[G3] = base + part[t];
}

// ---------------- pre-pass: all per-particle math, coalesced reads ----------------
__global__ void __launch_bounds__(256)
pre_kernel(const float* __restrict__ x, const float* __restrict__ v,
           const float* __restrict__ Cin, const float* __restrict__ Fin,
           const float* __restrict__ Jp_in, const int* __restrict__ material,
           const int* __restrict__ offset, int* __restrict__ cursor,
           PRec* __restrict__ rec, float* __restrict__ out, int N) {
    int n = blockIdx.x*256 + threadIdx.x;
    if (n >= N) return;

    float A0 = x[3*n+0]*c_INV_DX, A1 = x[3*n+1]*c_INV_DX, A2 = x[3*n+2]*c_INV_DX;
    int bi, bj, bk; float f0, f1, f2;
    base_from_A(A0, A1, A2, bi, bj, bk, f0, f1, f2);

    float Cm[9], Fm[9];
    #pragma unroll
    for (int i = 0; i < 9; ++i) { Cm[i] = Cin[9*n+i]; Fm[i] = Fin[9*n+i]; }

    // Fn = (I + DT*C) @ F
    float Fn[9];
    #pragma unroll
    for (int i = 0; i < 3; ++i)
        #pragma unroll
        for (int k = 0; k < 3; ++k) {
            float acc = Fm[i*3+k];
            #pragma unroll
            for (int j = 0; j < 3; ++j) acc += DT * Cm[i*3+j] * Fm[j*3+k];
            Fn[i*3+k] = acc;
        }

    float Jp = Jp_in[n];
    int mat = material[n];
    float h = expf(10.0f*(1.0f - Jp));
    h = fminf(fmaxf(h, 0.1f), 5.0f);
    if (mat == 1) h = 0.3f;
    float mu = (mat == 0) ? 0.0f : MU0*h;
    float la = LAM0*h;

    float U[9], V[9], sv[3];
    svd3(Fn, U, sv, V);

    float J = 1.0f;
    float sig[3];
    #pragma unroll
    for (int d = 0; d < 2; ++d) {
        float s = sv[d];
        float ns = (mat == 2) ? fminf(fmaxf(s, 1.0f-0.025f), 1.0f+0.0045f) : s;
        Jp = Jp * s / ns;
        sig[d] = ns;
        J *= ns;
    }
    sig[2] = sv[2];

    if (mat == 0) {
        float sj = sqrtf(J);
        Fn[0]=sj; Fn[1]=0; Fn[2]=0; Fn[3]=0; Fn[4]=sj; Fn[5]=0; Fn[6]=0; Fn[7]=0; Fn[8]=sj;
    } else if (mat == 2) {
        #pragma unroll
        for (int i = 0; i < 3; ++i)
            #pragma unroll
            for (int k = 0; k < 3; ++k) {
                float acc = 0.f;
                #pragma unroll
                for (int j = 0; j < 3; ++j) acc += U[i*3+j]*sig[j]*V[k*3+j];
                Fn[i*3+k] = acc;
            }
    }

    float R[9];
    #pragma unroll
    for (int i = 0; i < 3; ++i)
        #pragma unroll
        for (int k = 0; k < 3; ++k) {
            float acc = 0.f;
            #pragma unroll
            for (int j = 0; j < 3; ++j) acc += U[i*3+j]*V[k*3+j];
            R[i*3+k] = acc;
        }

    float press = la * J * (J - 1.0f);
    float scale = -DT * P_VOL * 4.0f * c_INV_DX * c_INV_DX;
    float aff[9];
    #pragma unroll
    for (int i = 0; i < 3; ++i)
        #pragma unroll
        for (int k = 0; k < 3; ++k) {
            float acc = 0.f;
            #pragma unroll
            for (int j = 0; j < 3; ++j) acc += (Fn[i*3+j]-R[i*3+j])*Fn[k*3+j];
            acc = 2.0f*mu*acc;
            if (i == k) acc += press;
            aff[i*3+k] = scale*acc + P_MASS*Cm[i*3+k];
        }

    float* po = out + (size_t)n*25;
    po[6] = Jp;
    #pragma unroll
    for (int i = 0; i < 9; ++i) po[7+i] = Fn[i];

    // cell-bucket slot
    int cell = (bi*NG + bj)*NG + bk;
    int pos = offset[cell] + atomicAdd(&cursor[cell], 1);

    float4* rp = (float4*)&rec[pos];
    rp[0] = make_float4(A0, A1, A2, __int_as_float(n));
    rp[1] = make_float4(aff[0], aff[1], aff[2], aff[3]);
    rp[2] = make_float4(aff[4], aff[5], aff[6], aff[7]);
    rp[3] = make_float4(aff[8], P_MASS*v[3*n+0], P_MASS*v[3*n+1], P_MASS*v[3*n+2]);
}

// ------- fused P2G-gather + grid update: one thread per 2 z-cells, NO atomics ----
// wave (64 lanes) = one full z-column (gi,gj wave-uniform)
__global__ void __launch_bounds__(256)
grid_gather_kernel(const PRec* __restrict__ rec, const int* __restrict__ offset,
                   float4* __restrict__ grid, const float* __restrict__ gravity,
                   const float* __restrict__ attr_s, const float* __restrict__ attr_p) {
    int g2 = blockIdx.x*256 + threadIdx.x;   // cell-pair index (G3/2 total)
    int gk2 = g2 & 63;
    int gj  = (g2 >> 6) & (NG-1);
    int gi  = g2 >> 13;
    int zlo = gk2*2, zhi = zlo+1;

    float a0x=0.f, a0y=0.f, a0z=0.f, m0=0.f;
    float a1x=0.f, a1y=0.f, a1z=0.f, m1=0.f;

    int bi0 = max(gi-2, 0), bi1 = min(gi, NG-3);
    int bj0 = max(gj-2, 0), bj1 = min(gj, NG-3);
    int bk0 = max(zlo-2, 0), bk1 = min(zhi, NG-3);

    float gif = (float)gi, gjf = (float)gj, z0f = (float)zlo;

    for (int bi = bi0; bi <= bi1; ++bi) {
        for (int bj = bj0; bj <= bj1; ++bj) {
            int col = (bi*NG + bj)*NG;
            int s = offset[col + bk0];
            int e = offset[col + bk1 + 1];
            for (int p = s; p < e; ++p) {
                const float4* rp = (const float4*)&rec[p];
                float4 r0 = rp[0];
                float4 r1 = rp[1];
                float4 r2 = rp[2];
                float4 r3 = rp[3];

                // quadratic B-spline via symmetric kernel N(u), u = cell - A
                // (fp-exact match to reference: u = off - fx bitwise)
                float ux = gif - r0.x;
                float aux = fabsf(ux);
                float tx = 1.5f - aux;
                float nx = (aux < 0.5f) ? (0.75f - ux*ux) : (0.5f*tx*tx);
                float uy = gjf - r0.y;
                float auy = fabsf(uy);
                float ty = 1.5f - auy;
                float ny = (auy < 0.5f) ? (0.75f - uy*uy) : (0.5f*ty*ty);
                float wgt = nx*ny;                 // reference: x,y weights only

                float uz0 = z0f - r0.z;
                float uz1 = uz0 + 1.0f;
                // z-validity (mass has no z-weight; must mask by bucket membership):
                // valid <=> uz in (-1.5, 1.5]
                float w0 = (uz0 > -1.5f && uz0 <= 1.5f) ? wgt : 0.f;
                float w1 = (uz1 > -1.5f && uz1 <= 1.5f) ? wgt : 0.f;

                float dpx = ux*c_DX, dpy = uy*c_DX, dpz0 = uz0*c_DX;
                float sx = r3.y + r1.x*dpx + r1.y*dpy;
                float sy = r3.z + r1.w*dpx + r2.x*dpy;
                float sz = r3.w + r2.z*dpx + r2.w*dpy;
                float c0x = sx + r1.z*dpz0;
                float c0y = sy + r2.y*dpz0;
                float c0z = sz + r3.x*dpz0;
                float c1x = c0x + r1.z*c_DX;
                float c1y = c0y + r2.y*c_DX;
                float c1z = c0z + r3.x*c_DX;
                a0x += w0*c0x; a0y += w0*c0y; a0z += w0*c0z; m0 += w0*P_MASS;
                a1x += w1*c1x; a1y += w1*c1y; a1z += w1*c1z; m1 += w1*P_MASS;
            }
        }
    }

    // finalize both cells
    float gx = DT*gravity[0]*30.0f, gy = DT*gravity[1]*30.0f, gz = DT*gravity[2]*30.0f;
    float apx = attr_p[0], apy = attr_p[1], apz = attr_p[2];
    float as  = attr_s[0] * DT * 100.0f;

    int gidx = (gi*NG + gj)*NG + zlo;
    #pragma unroll
    for (int h = 0; h < 2; ++h) {
        float m   = h ? m1 : m0;
        float mx  = h ? a1x : a0x;
        float my  = h ? a1y : a0y;
        float mz  = h ? a1z : a0z;
        int   gk  = zlo + h;
        float gvx = 0.f, gvy = 0.f, gvz = 0.f;
        if (m > 0.f) {
            float inv = 1.0f/m;
            gvx = mx*inv + gx; gvy = my*inv + gy; gvz = mz*inv + gz;
            float dx_ = apx - c_DX*(float)gi;
            float dy_ = apy - c_DX*(float)gj;
            float dz_ = apz - c_DX*(float)gk;
            float nrm = sqrtf(dx_*dx_ + dy_*dy_ + dz_*dz_);
            float sc = as / (0.01f + nrm);
            gvx += dx_*sc; gvy += dy_*sc; gvz += dz_*sc;
            if (gi < 3      && gvx < 0.f) gvx = 0.f;
            if (gi > NG-3   && gvx > 0.f) gvx = 0.f;
            if (gj < 3      && gvy < 0.f) gvy = 0.f;
            if (gj > NG-3   && gvy > 0.f) gvy = 0.f;
            // z unconstrained (matches reference)
        }
        grid[gidx + h] = make_float4(gvx, gvy, gvz, m);
    }
}

// ---------------- G2P (cell-sorted order, coalesced record reads) ----------------
__global__ void __launch_bounds__(256)
g2p_kernel(const PRec* __restrict__ rec, const float4* __restrict__ grid,
           float* __restrict__ out, int N) {
    int gid = blockIdx.x * 256 + threadIdx.x;
    if (gid >= N) return;

    float4 r0 = rec[gid].r0;
    float A0 = r0.x, A1 = r0.y, A2 = r0.z;
    int n = __float_as_int(r0.w);

    int bi, bj, bk; float fx0, fx1, fx2;
    base_from_A(A0, A1, A2, bi, bj, bk, fx0, fx1, fx2);

    float wx[3], wy[3];
    wx[0] = 0.5f*(1.5f-fx0)*(1.5f-fx0); wx[1] = 0.75f-(fx0-1.f)*(fx0-1.f); wx[2] = 0.5f*(fx0-0.5f)*(fx0-0.5f);
    wy[0] = 0.5f*(1.5f-fx1)*(1.5f-fx1); wy[1] = 0.75f-(fx1-1.f)*(fx1-1.f); wy[2] = 0.5f*(fx1-0.5f)*(fx1-0.5f);

    float nvx = 0.f, nvy = 0.f, nvz = 0.f;
    float nC[9];
    #pragma unroll
    for (int i = 0; i < 9; ++i) nC[i] = 0.f;

    #pragma unroll
    for (int i = 0; i < 3; ++i) {
        float dpx = (float)i - fx0;
        #pragma unroll
        for (int j = 0; j < 3; ++j) {
            float wgt = wx[i]*wy[j];
            float dpy = (float)j - fx1;
            int cell0 = ((bi+i)*NG + (bj+j))*NG + bk;
            #pragma unroll
            for (int k = 0; k < 3; ++k) {
                float dpz = (float)k - fx2;
                float4 gv = grid[cell0 + k];
                float wgx = wgt*gv.x, wgy = wgt*gv.y, wgz = wgt*gv.z;
                nvx += wgx; nvy += wgy; nvz += wgz;
                nC[0] += wgx*dpx; nC[1] += wgx*dpy; nC[2] += wgx*dpz;
                nC[3] += wgy*dpx; nC[4] += wgy*dpy; nC[5] += wgy*dpz;
                nC[6] += wgz*dpx; nC[7] += wgz*dpy; nC[8] += wgz*dpz;
            }
        }
    }

    float* po = out + (size_t)n*25;
    float px = A0*c_DX, py = A1*c_DX, pz = A2*c_DX;   // exact reconstruction
    po[0] = px + DT*nvx;
    po[1] = py + DT*nvy;
    po[2] = pz + DT*nvz;
    po[3] = nvx; po[4] = nvy; po[5] = nvz;
    float s4 = 4.0f*c_INV_DX;
    #pragma unroll
    for (int i = 0; i < 9; ++i) po[16+i] = s4*nC[i];
}

extern "C" void kernel_launch(void* const* d_in, const int* in_sizes, int n_in,
                              void* d_out, int out_size, void* d_ws, size_t ws_size,
                              hipStream_t stream) {
    const float* x        = (const float*)d_in[0];
    const float* v        = (const float*)d_in[1];
    const float* C        = (const float*)d_in[2];
    const float* F        = (const float*)d_in[3];
    const float* Jp       = (const float*)d_in[4];
    const float* gravity  = (const float*)d_in[5];
    const float* attr_s   = (const float*)d_in[6];
    const float* attr_p   = (const float*)d_in[7];
    const int*   material = (const int*)d_in[8];
    float* out = (float*)d_out;
    int N = in_sizes[0] / 3;

    // workspace: [count G3][cursor G3] (zeroed) [offset G3+1][partial 8192][grid][rec]
    char* ws = (char*)d_ws;
    size_t o = 0;
    int* cell_count = (int*)(ws + o);      o += (size_t)G3*sizeof(int);
    int* cursor     = (int*)(ws + o);      o += (size_t)G3*sizeof(int);
    size_t zero_bytes = o;
    int* offset     = (int*)(ws + o);      o += ((size_t)G3+1)*sizeof(int);
    int* partial    = (int*)(ws + o);      o += (size_t)NSCAN_BLOCKS*sizeof(int);
    o = (o + 127) & ~(size_t)127;
    float4* grid    = (float4*)(ws + o);   o += (size_t)G3*sizeof(float4);
    PRec* rec       = (PRec*)(ws + o);     o += (size_t)N*sizeof(PRec);

    hipMemsetAsync(d_ws, 0, zero_bytes, stream);

    int pblocks = (N + 255) / 256;
    count_kernel<<<pblocks, 256, 0, stream>>>(x, cell_count, N);
    scan_partial_kernel<<<NSCAN_BLOCKS, 256, 0, stream>>>(cell_count, partial);
    scan_partials_kernel<<<1, 256, 0, stream>>>(partial);
    scan_final_kernel<<<NSCAN_BLOCKS, 256, 0, stream>>>(cell_count, partial, offset);
    pre_kernel<<<pblocks, 256, 0, stream>>>(x, v, C, F, Jp, material,
                                            offset, cursor, rec, out, N);
    grid_gather_kernel<<<G3/512, 256, 0, stream>>>(rec, offset, grid,
                                                   gravity, attr_s, attr_p);
    g2p_kernel<<<pblocks, 256, 0, stream>>>(rec, grid, out, N);
}

// Round 8
// 277.539 us; speedup vs baseline: 2.0070x; 1.0677x over previous
//
#include <hip/hip_runtime.h>

#define NG 128
#define G3 (NG*NG*NG)
#define NSCAN_BLOCKS (G3/256)   // 8192

__device__ __constant__ const float c_DX      = 1.0f/128.0f;
__device__ __constant__ const float c_INV_DX  = 128.0f;

#define DT      1e-4f
#define P_VOL   ((1.0f/256.0f)*(1.0f/256.0f))
#define P_MASS  P_VOL
#define MU0     (5000.0f/(2.0f*1.2f))
#define LAM0    (5000.0f*0.2f/(1.2f*0.6f))

// 64-byte packed particle record, stored in cell-bucket order
// r0 = {A0, A1, A2, particle_id}   A = x*INV_DX (absolute grid coord; exact)
// r1 = {aff0..3}, r2 = {aff4..7}, r3 = {aff8, mv0, mv1, mv2}
struct __align__(16) PRec {
    float4 r0, r1, r2, r3;
};

// ---------------- 3x3 SVD via Jacobi on A^T A ----------------
__device__ inline void jacobi_rot(float S[3][3], float V[3][3], int p, int q) {
    float apq = S[p][q];
    if (fabsf(apq) < 1e-24f) return;
    float tau = (S[q][q] - S[p][p]) / (2.0f * apq);
    float t = copysignf(1.0f, tau) / (fabsf(tau) + sqrtf(1.0f + tau*tau));
    float c = rsqrtf(1.0f + t*t);
    float sn = t * c;
    #pragma unroll
    for (int k = 0; k < 3; ++k) {
        float Spk = S[p][k], Sqk = S[q][k];
        S[p][k] = c*Spk - sn*Sqk;
        S[q][k] = sn*Spk + c*Sqk;
    }
    #pragma unroll
    for (int k = 0; k < 3; ++k) {
        float Skp = S[k][p], Skq = S[k][q];
        S[k][p] = c*Skp - sn*Skq;
        S[k][q] = sn*Skp + c*Skq;
    }
    #pragma unroll
    for (int k = 0; k < 3; ++k) {
        float Vkp = V[k][p], Vkq = V[k][q];
        V[k][p] = c*Vkp - sn*Vkq;
        V[k][q] = sn*Vkp + c*Vkq;
    }
}

__device__ inline void svd3(const float A[9], float U[9], float sv[3], float V[9]) {
    float S[3][3];
    #pragma unroll
    for (int i = 0; i < 3; ++i)
        #pragma unroll
        for (int j = 0; j < 3; ++j) {
            float acc = 0.f;
            #pragma unroll
            for (int k = 0; k < 3; ++k) acc += A[k*3+i]*A[k*3+j];
            S[i][j] = acc;
        }
    float Vm[3][3] = {{1.f,0.f,0.f},{0.f,1.f,0.f},{0.f,0.f,1.f}};
    #pragma unroll
    for (int sweep = 0; sweep < 4; ++sweep) {
        jacobi_rot(S, Vm, 0, 1);
        jacobi_rot(S, Vm, 0, 2);
        jacobi_rot(S, Vm, 1, 2);
    }
    float lam[3] = {S[0][0], S[1][1], S[2][2]};
    int i0 = 0, i1 = 1, i2 = 2, t;
    if (lam[i0] < lam[i1]) { t = i0; i0 = i1; i1 = t; }
    if (lam[i0] < lam[i2]) { t = i0; i0 = i2; i2 = t; }
    if (lam[i1] < lam[i2]) { t = i1; i1 = i2; i2 = t; }
    int ord[3] = {i0, i1, i2};
    #pragma unroll
    for (int c = 0; c < 3; ++c) {
        int s_ = ord[c];
        float l = fmaxf(lam[s_], 0.f);
        float sval = sqrtf(l);
        sv[c] = sval;
        float v0 = Vm[0][s_], v1 = Vm[1][s_], v2 = Vm[2][s_];
        V[0*3+c] = v0; V[1*3+c] = v1; V[2*3+c] = v2;
        float inv = (sval > 1e-12f) ? 1.0f/sval : 0.f;
        U[0*3+c] = (A[0]*v0 + A[1]*v1 + A[2]*v2)*inv;
        U[1*3+c] = (A[3]*v0 + A[4]*v1 + A[5]*v2)*inv;
        U[2*3+c] = (A[6]*v0 + A[7]*v1 + A[8]*v2)*inv;
    }
}

// ---------------- binning helpers ----------------
// from absolute grid coord A: base cell + frac (all fp-exact)
__device__ inline void base_from_A(float A0, float A1, float A2,
                                   int& bi, int& bj, int& bk,
                                   float& fx0, float& fx1, float& fx2) {
    float bxf = floorf(A0 - 0.5f);
    float byf = floorf(A1 - 0.5f);
    float bzf = floorf(A2 - 0.5f);
    bi = (int)bxf; bj = (int)byf; bk = (int)bzf;
    bi = min(max(bi, 0), NG-3); bj = min(max(bj, 0), NG-3); bk = min(max(bk, 0), NG-3);
    fx0 = A0 - bxf;
    fx1 = A1 - byf;
    fx2 = A2 - bzf;
}

// count + per-particle rank within its cell (atomicAdd's return value)
__global__ void __launch_bounds__(256)
count_kernel(const float* __restrict__ x, int* __restrict__ cell_count,
             int* __restrict__ rank, int N) {
    int n = blockIdx.x*256 + threadIdx.x;
    if (n >= N) return;
    int bi, bj, bk; float f0, f1, f2;
    base_from_A(x[3*n+0]*c_INV_DX, x[3*n+1]*c_INV_DX, x[3*n+2]*c_INV_DX,
                bi, bj, bk, f0, f1, f2);
    rank[n] = atomicAdd(&cell_count[(bi*NG + bj)*NG + bk], 1);
}

// ---- scan stage A: per-block (256 elems) reduction -> partial[block] ----
__global__ void __launch_bounds__(256)
scan_partial_kernel(const int* __restrict__ count, int* __restrict__ partial) {
    __shared__ int red[256];
    int t = threadIdx.x;
    red[t] = count[blockIdx.x*256 + t];
    __syncthreads();
    for (int off = 128; off > 0; off >>= 1) {
        if (t < off) red[t] += red[t+off];
        __syncthreads();
    }
    if (t == 0) partial[blockIdx.x] = red[0];
}

// ---- scan stage B: exclusive scan of 8192 partials, 1 block, 256x32 ----
__global__ void __launch_bounds__(256)
scan_partials_kernel(int* __restrict__ partial) {
    __shared__ int part[256];
    int t = threadIdx.x;
    int base = t*32;
    int local[32];
    int s = 0;
    #pragma unroll
    for (int i = 0; i < 32; ++i) { local[i] = s; s += partial[base+i]; }
    part[t] = s;
    __syncthreads();
    for (int off = 1; off < 256; off <<= 1) {
        int v = (t >= off) ? part[t-off] : 0;
        __syncthreads();
        part[t] += v;
        __syncthreads();
    }
    int prev = (t == 0) ? 0 : part[t-1];
    #pragma unroll
    for (int i = 0; i < 32; ++i) partial[base+i] = prev + local[i];
}

// ---- scan stage C: block-level exclusive scan + partial base -> offset ----
__global__ void __launch_bounds__(256)
scan_final_kernel(const int* __restrict__ count, const int* __restrict__ partial,
                  int* __restrict__ offset) {
    __shared__ int part[256];
    int t = threadIdx.x;
    int i = blockIdx.x*256 + t;
    int c = count[i];
    part[t] = c;
    __syncthreads();
    for (int off = 1; off < 256; off <<= 1) {
        int v = (t >= off) ? part[t-off] : 0;
        __syncthreads();
        part[t] += v;
        __syncthreads();
    }
    int base = partial[blockIdx.x];
    offset[i] = base + part[t] - c;
    if (i == G3-1) offset[G3] = base + part[t];
}

// ---------------- pre-pass: all per-particle math, coalesced reads ----------------
__global__ void __launch_bounds__(256)
pre_kernel(const float* __restrict__ x, const float* __restrict__ v,
           const float* __restrict__ Cin, const float* __restrict__ Fin,
           const float* __restrict__ Jp_in, const int* __restrict__ material,
           const int* __restrict__ offset, const int* __restrict__ rank,
           PRec* __restrict__ rec, float* __restrict__ out, int N) {
    int n = blockIdx.x*256 + threadIdx.x;
    if (n >= N) return;

    float A0 = x[3*n+0]*c_INV_DX, A1 = x[3*n+1]*c_INV_DX, A2 = x[3*n+2]*c_INV_DX;
    int bi, bj, bk; float f0, f1, f2;
    base_from_A(A0, A1, A2, bi, bj, bk, f0, f1, f2);

    float Cm[9], Fm[9];
    #pragma unroll
    for (int i = 0; i < 9; ++i) { Cm[i] = Cin[9*n+i]; Fm[i] = Fin[9*n+i]; }

    // Fn = (I + DT*C) @ F
    float Fn[9];
    #pragma unroll
    for (int i = 0; i < 3; ++i)
        #pragma unroll
        for (int k = 0; k < 3; ++k) {
            float acc = Fm[i*3+k];
            #pragma unroll
            for (int j = 0; j < 3; ++j) acc += DT * Cm[i*3+j] * Fm[j*3+k];
            Fn[i*3+k] = acc;
        }

    float Jp = Jp_in[n];
    int mat = material[n];
    float h = expf(10.0f*(1.0f - Jp));
    h = fminf(fmaxf(h, 0.1f), 5.0f);
    if (mat == 1) h = 0.3f;
    float mu = (mat == 0) ? 0.0f : MU0*h;
    float la = LAM0*h;

    float U[9], V[9], sv[3];
    svd3(Fn, U, sv, V);

    float J = 1.0f;
    float sig[3];
    #pragma unroll
    for (int d = 0; d < 2; ++d) {
        float s = sv[d];
        float ns = (mat == 2) ? fminf(fmaxf(s, 1.0f-0.025f), 1.0f+0.0045f) : s;
        Jp = Jp * s / ns;
        sig[d] = ns;
        J *= ns;
    }
    sig[2] = sv[2];

    if (mat == 0) {
        float sj = sqrtf(J);
        Fn[0]=sj; Fn[1]=0; Fn[2]=0; Fn[3]=0; Fn[4]=sj; Fn[5]=0; Fn[6]=0; Fn[7]=0; Fn[8]=sj;
    } else if (mat == 2) {
        #pragma unroll
        for (int i = 0; i < 3; ++i)
            #pragma unroll
            for (int k = 0; k < 3; ++k) {
                float acc = 0.f;
                #pragma unroll
                for (int j = 0; j < 3; ++j) acc += U[i*3+j]*sig[j]*V[k*3+j];
                Fn[i*3+k] = acc;
            }
    }

    float R[9];
    #pragma unroll
    for (int i = 0; i < 3; ++i)
        #pragma unroll
        for (int k = 0; k < 3; ++k) {
            float acc = 0.f;
            #pragma unroll
            for (int j = 0; j < 3; ++j) acc += U[i*3+j]*V[k*3+j];
            R[i*3+k] = acc;
        }

    float press = la * J * (J - 1.0f);
    float scale = -DT * P_VOL * 4.0f * c_INV_DX * c_INV_DX;
    float aff[9];
    #pragma unroll
    for (int i = 0; i < 3; ++i)
        #pragma unroll
        for (int k = 0; k < 3; ++k) {
            float acc = 0.f;
            #pragma unroll
            for (int j = 0; j < 3; ++j) acc += (Fn[i*3+j]-R[i*3+j])*Fn[k*3+j];
            acc = 2.0f*mu*acc;
            if (i == k) acc += press;
            aff[i*3+k] = scale*acc + P_MASS*Cm[i*3+k];
        }

    float* po = out + (size_t)n*25;
    po[6] = Jp;
    #pragma unroll
    for (int i = 0; i < 9; ++i) po[7+i] = Fn[i];

    // cell-bucket slot (rank captured by count_kernel's atomicAdd)
    int cell = (bi*NG + bj)*NG + bk;
    int pos = offset[cell] + rank[n];

    float4* rp = (float4*)&rec[pos];
    rp[0] = make_float4(A0, A1, A2, __int_as_float(n));
    rp[1] = make_float4(aff[0], aff[1], aff[2], aff[3]);
    rp[2] = make_float4(aff[4], aff[5], aff[6], aff[7]);
    rp[3] = make_float4(aff[8], P_MASS*v[3*n+0], P_MASS*v[3*n+1], P_MASS*v[3*n+2]);
}

// ------- fused P2G-gather + grid update: one thread per 4 z-cells, NO atomics ----
__global__ void __launch_bounds__(256)
grid_gather_kernel(const PRec* __restrict__ rec, const int* __restrict__ offset,
                   float4* __restrict__ grid, const float* __restrict__ gravity,
                   const float* __restrict__ attr_s, const float* __restrict__ attr_p) {
    int g4 = blockIdx.x*256 + threadIdx.x;   // quad index (G3/4 total)
    int zq = g4 & 31;
    int gj = (g4 >> 5) & (NG-1);
    int gi = g4 >> 12;
    int zlo = zq*4;

    float ax[4], ay[4], az[4], mm[4];
    #pragma unroll
    for (int h = 0; h < 4; ++h) { ax[h]=0.f; ay[h]=0.f; az[h]=0.f; mm[h]=0.f; }

    int bi0 = max(gi-2, 0), bi1 = min(gi, NG-3);
    int bj0 = max(gj-2, 0), bj1 = min(gj, NG-3);
    int bk0 = max(zlo-2, 0), bk1 = min(zlo+3, NG-3);

    float gif = (float)gi, gjf = (float)gj, z0f = (float)zlo;
    bool any = false;

    for (int bi = bi0; bi <= bi1; ++bi) {
        for (int bj = bj0; bj <= bj1; ++bj) {
            int col = (bi*NG + bj)*NG;
            int s = offset[col + bk0];
            int e = offset[col + bk1 + 1];
            if (s < e) any = true;
            for (int p = s; p < e; ++p) {
                const float4* rp = (const float4*)&rec[p];
                float4 r0 = rp[0];
                float4 r1 = rp[1];
                float4 r2 = rp[2];
                float4 r3 = rp[3];

                // symmetric quadratic B-spline N(u), u = cell - A (fp-exact vs ref)
                float ux = gif - r0.x;
                float aux = fabsf(ux);
                float tx = 1.5f - aux;
                float nx = (aux < 0.5f) ? (0.75f - ux*ux) : (0.5f*tx*tx);
                float uy = gjf - r0.y;
                float auy = fabsf(uy);
                float ty = 1.5f - auy;
                float ny = (auy < 0.5f) ? (0.75f - uy*uy) : (0.5f*ty*ty);
                float wgt = nx*ny;                 // reference: x,y weights only

                float uz0 = z0f - r0.z;
                float dpx = ux*c_DX, dpy = uy*c_DX, dpz0 = uz0*c_DX;
                float cx = r3.y + r1.x*dpx + r1.y*dpy + r1.z*dpz0;
                float cy = r3.z + r1.w*dpx + r2.x*dpy + r2.y*dpz0;
                float cz = r3.w + r2.z*dpx + r2.w*dpy + r3.x*dpz0;
                float ix = r1.z*c_DX, iy = r2.y*c_DX, iz = r3.x*c_DX;

                #pragma unroll
                for (int h = 0; h < 4; ++h) {
                    float uz = uz0 + (float)h;
                    // membership mask: uz in (-1.5, 1.5]
                    float w = (uz > -1.5f && uz <= 1.5f) ? wgt : 0.f;
                    ax[h] += w*cx; ay[h] += w*cy; az[h] += w*cz; mm[h] += w*P_MASS;
                    cx += ix; cy += iy; cz += iz;
                }
            }
        }
    }

    // quads with zero visits are never read by g2p (any cell g2p reads has a
    // member particle, and member particles lie in this quad's bucket window)
    if (!any) return;

    float gx = DT*gravity[0]*30.0f, gy = DT*gravity[1]*30.0f, gz = DT*gravity[2]*30.0f;
    float apx = attr_p[0], apy = attr_p[1], apz = attr_p[2];
    float as  = attr_s[0] * DT * 100.0f;

    int gidx = (gi*NG + gj)*NG + zlo;
    #pragma unroll
    for (int h = 0; h < 4; ++h) {
        float m = mm[h];
        int gk = zlo + h;
        float gvx = 0.f, gvy = 0.f, gvz = 0.f;
        if (m > 0.f) {
            float inv = 1.0f/m;
            gvx = ax[h]*inv + gx; gvy = ay[h]*inv + gy; gvz = az[h]*inv + gz;
            float dx_ = apx - c_DX*(float)gi;
            float dy_ = apy - c_DX*(float)gj;
            float dz_ = apz - c_DX*(float)gk;
            float nrm = sqrtf(dx_*dx_ + dy_*dy_ + dz_*dz_);
            float sc = as / (0.01f + nrm);
            gvx += dx_*sc; gvy += dy_*sc; gvz += dz_*sc;
            if (gi < 3      && gvx < 0.f) gvx = 0.f;
            if (gi > NG-3   && gvx > 0.f) gvx = 0.f;
            if (gj < 3      && gvy < 0.f) gvy = 0.f;
            if (gj > NG-3   && gvy > 0.f) gvy = 0.f;
            // z unconstrained (matches reference)
        }
        grid[gidx + h] = make_float4(gvx, gvy, gvz, m);
    }
}

// ---------------- G2P (cell-sorted order, coalesced record reads) ----------------
__global__ void __launch_bounds__(256)
g2p_kernel(const PRec* __restrict__ rec, const float4* __restrict__ grid,
           float* __restrict__ out, int N) {
    int gid = blockIdx.x * 256 + threadIdx.x;
    if (gid >= N) return;

    float4 r0 = rec[gid].r0;
    float A0 = r0.x, A1 = r0.y, A2 = r0.z;
    int n = __float_as_int(r0.w);

    int bi, bj, bk; float fx0, fx1, fx2;
    base_from_A(A0, A1, A2, bi, bj, bk, fx0, fx1, fx2);

    float wx[3], wy[3];
    wx[0] = 0.5f*(1.5f-fx0)*(1.5f-fx0); wx[1] = 0.75f-(fx0-1.f)*(fx0-1.f); wx[2] = 0.5f*(fx0-0.5f)*(fx0-0.5f);
    wy[0] = 0.5f*(1.5f-fx1)*(1.5f-fx1); wy[1] = 0.75f-(fx1-1.f)*(fx1-1.f); wy[2] = 0.5f*(fx1-0.5f)*(fx1-0.5f);

    float nvx = 0.f, nvy = 0.f, nvz = 0.f;
    float nC[9];
    #pragma unroll
    for (int i = 0; i < 9; ++i) nC[i] = 0.f;

    #pragma unroll
    for (int i = 0; i < 3; ++i) {
        float dpx = (float)i - fx0;
        #pragma unroll
        for (int j = 0; j < 3; ++j) {
            float wgt = wx[i]*wy[j];
            float dpy = (float)j - fx1;
            int cell0 = ((bi+i)*NG + (bj+j))*NG + bk;
            #pragma unroll
            for (int k = 0; k < 3; ++k) {
                float dpz = (float)k - fx2;
                float4 gv = grid[cell0 + k];
                float wgx = wgt*gv.x, wgy = wgt*gv.y, wgz = wgt*gv.z;
                nvx += wgx; nvy += wgy; nvz += wgz;
                nC[0] += wgx*dpx; nC[1] += wgx*dpy; nC[2] += wgx*dpz;
                nC[3] += wgy*dpx; nC[4] += wgy*dpy; nC[5] += wgy*dpz;
                nC[6] += wgz*dpx; nC[7] += wgz*dpy; nC[8] += wgz*dpz;
            }
        }
    }

    float* po = out + (size_t)n*25;
    float px = A0*c_DX, py = A1*c_DX, pz = A2*c_DX;   // exact reconstruction
    po[0] = px + DT*nvx;
    po[1] = py + DT*nvy;
    po[2] = pz + DT*nvz;
    po[3] = nvx; po[4] = nvy; po[5] = nvz;
    float s4 = 4.0f*c_INV_DX;
    #pragma unroll
    for (int i = 0; i < 9; ++i) po[16+i] = s4*nC[i];
}

extern "C" void kernel_launch(void* const* d_in, const int* in_sizes, int n_in,
                              void* d_out, int out_size, void* d_ws, size_t ws_size,
                              hipStream_t stream) {
    const float* x        = (const float*)d_in[0];
    const float* v        = (const float*)d_in[1];
    const float* C        = (const float*)d_in[2];
    const float* F        = (const float*)d_in[3];
    const float* Jp       = (const float*)d_in[4];
    const float* gravity  = (const float*)d_in[5];
    const float* attr_s   = (const float*)d_in[6];
    const float* attr_p   = (const float*)d_in[7];
    const int*   material = (const int*)d_in[8];
    float* out = (float*)d_out;
    int N = in_sizes[0] / 3;

    // workspace: [count G3] (zeroed) [offset G3+1][partial][rank N][grid][rec]
    char* ws = (char*)d_ws;
    size_t o = 0;
    int* cell_count = (int*)(ws + o);      o += (size_t)G3*sizeof(int);
    size_t zero_bytes = o;
    int* offset     = (int*)(ws + o);      o += ((size_t)G3+1)*sizeof(int);
    int* partial    = (int*)(ws + o);      o += (size_t)NSCAN_BLOCKS*sizeof(int);
    int* rank       = (int*)(ws + o);      o += (size_t)N*sizeof(int);
    o = (o + 127) & ~(size_t)127;
    float4* grid    = (float4*)(ws + o);   o += (size_t)G3*sizeof(float4);
    PRec* rec       = (PRec*)(ws + o);     o += (size_t)N*sizeof(PRec);

    hipMemsetAsync(d_ws, 0, zero_bytes, stream);

    int pblocks = (N + 255) / 256;
    count_kernel<<<pblocks, 256, 0, stream>>>(x, cell_count, rank, N);
    scan_partial_kernel<<<NSCAN_BLOCKS, 256, 0, stream>>>(cell_count, partial);
    scan_partials_kernel<<<1, 256, 0, stream>>>(partial);
    scan_final_kernel<<<NSCAN_BLOCKS, 256, 0, stream>>>(cell_count, partial, offset);
    pre_kernel<<<pblocks, 256, 0, stream>>>(x, v, C, F, Jp, material,
                                            offset, rank, rec, out, N);
    grid_gather_kernel<<<G3/1024, 256, 0, stream>>>(rec, offset, grid,
                                                    gravity, attr_s, attr_p);
    g2p_kernel<<<pblocks, 256, 0, stream>>>(rec, grid, out, N);
}